// Round 11
// baseline (512.794 us; speedup 1.0000x reference)
//
#include <hip/hip_runtime.h>
#include <hip/hip_bf16.h>

typedef unsigned short u16;
typedef u16 u16x8 __attribute__((ext_vector_type(8)));
typedef short s16x8 __attribute__((ext_vector_type(8)));
typedef float f32x4 __attribute__((ext_vector_type(4)));
typedef unsigned int u32;

#define NN 24
#define TT 49
#define MR 784                  // B*T = 16*49
#define SZT 4816896             // B*T*N*H

__device__ inline u16 f2b(float f){
    __hip_bfloat16 b = __float2bfloat16(f); u16 r; __builtin_memcpy(&r, &b, 2); return r;
}
__device__ inline float sig_(float x){ return 1.f / (1.f + __expf(-x)); }
__device__ inline float tanh_(float x){ float e = __expf(2.f * x); return (e - 1.f) / (e + 1.f); }

__device__ inline void gld16(const u16* g, u16* l){
    __builtin_amdgcn_global_load_lds(
        (const __attribute__((address_space(1))) unsigned int*)g,
        (__attribute__((address_space(3))) unsigned int*)l, 16, 0, 0);
}

#define BAR()      __builtin_amdgcn_s_barrier()
#define WAITVL(N)  asm volatile("s_waitcnt vmcnt(" #N ") lgkmcnt(0)" ::: "memory")

// ws layout: WT0 bf16 [216][56][256][32] | WT1 bf16 [144][16][256][32]
#define WT0_ELEMS ((size_t)216 * 256 * 1792)
#define WT1_ELEMS ((size_t)144 * 256 * 512)

// ===========================================================================
// Weight prepass: wprep0 (24192 blk) | wprep1 (4608 blk)
// f32 [k][col] -> bf16 k-tiled [kt][col][32], concat per slab.
// ===========================================================================
__global__ __launch_bounds__(256) void prep_w(
    const float* __restrict__ U,  const float* __restrict__ Wt,
    const float* __restrict__ Ws, const float* __restrict__ Zt,
    const float* __restrict__ Zs, const float* __restrict__ Wg,
    const float* __restrict__ Zg,
    u16* __restrict__ wt0, u16* __restrict__ wt1)
{
    __shared__ u16 T[64][72];
    const int tid = threadIdx.x;
    const int lin = blockIdx.x;

    if (lin < 24192) {
        const int kt = lin % 28, ct = (lin / 28) % 4, z = lin / 112;
        const int n = z % NN, g = z / NN;
        const int k0 = kt * 64;
        const float* wbase;
        if (k0 < 256)       wbase = U  + (size_t)((g * NN + n) * 256 + k0)          * 256;
        else if (k0 < 1024) wbase = Wt + (size_t)((g * NN + n) * 768 + (k0 - 256))  * 256;
        else if (k0 < 1280) wbase = Ws + (size_t)((g * NN + n) * 256 + (k0 - 1024)) * 256;
        else if (k0 < 1536) wbase = Zt + (size_t)((g * NN + n) * 256 + (k0 - 1280)) * 256;
        else { const int g2 = (g == 2) ? 1 : g;      // Zs_eff: f_ft uses Zs[lt]
               wbase = Zs + (size_t)((g2 * NN + n) * 256 + (k0 - 1536)) * 256; }
        const int colg = ct * 64 + (tid & 15) * 4;
        #pragma unroll
        for (int it = 0; it < 4; ++it) {
            const int krl = (tid >> 4) + it * 16;
            const float4 v = *(const float4*)(wbase + (size_t)krl * 256 + colg);
            const int cl = (tid & 15) * 4;
            T[cl + 0][krl] = f2b(v.x); T[cl + 1][krl] = f2b(v.y);
            T[cl + 2][krl] = f2b(v.z); T[cl + 3][krl] = f2b(v.w);
        }
        __syncthreads();
        const int col_l = tid >> 2, ks = (tid & 3) * 16;
        const int ktile = 2 * kt + (ks >> 5);
        const int koff  = ks & 31;
        u16* dst = wt0 + (size_t)z * 458752 + (size_t)ktile * 8192
                       + (size_t)(ct * 64 + col_l) * 32 + koff;
        u16x8 w0, w1;
        #pragma unroll
        for (int j2 = 0; j2 < 8; ++j2) { w0[j2] = T[col_l][ks + j2]; w1[j2] = T[col_l][ks + 8 + j2]; }
        *(u16x8*)(dst) = w0; *(u16x8*)(dst + 8) = w1;
    } else {
        const int l = lin - 24192;
        const int kt = l % 8, ct = (l / 8) % 4, z = l / 32;
        const int k0 = kt * 64;
        const float* wbase = (k0 < 256)
            ? Wg + (size_t)(z * 256 + k0) * 256
            : Zg + (size_t)(z * 256 + (k0 - 256)) * 256;
        const int colg = ct * 64 + (tid & 15) * 4;
        #pragma unroll
        for (int it = 0; it < 4; ++it) {
            const int krl = (tid >> 4) + it * 16;
            const float4 v = *(const float4*)(wbase + (size_t)krl * 256 + colg);
            const int cl = (tid & 15) * 4;
            T[cl + 0][krl] = f2b(v.x); T[cl + 1][krl] = f2b(v.y);
            T[cl + 2][krl] = f2b(v.z); T[cl + 3][krl] = f2b(v.w);
        }
        __syncthreads();
        const int col_l = tid >> 2, ks = (tid & 3) * 16;
        const int ktile = 2 * kt + (ks >> 5);
        const int koff  = ks & 31;
        u16* dst = wt1 + (size_t)z * 131072 + (size_t)ktile * 8192
                       + (size_t)(ct * 64 + col_l) * 32 + koff;
        u16x8 w0, w1;
        #pragma unroll
        for (int j2 = 0; j2 < 8; ++j2) { w0[j2] = T[col_l][ks + j2]; w1[j2] = T[col_l][ks + 8 + j2]; }
        *(u16x8*)(dst) = w0; *(u16x8*)(dst + 8) = w1;
    }
}

// ===========================================================================
// Phase 0: counted-vmcnt pipeline; B via global_load_lds DMA; A split-staged
// in-kernel from f32 (loadA early -> regs, storeA late -> LDS, T14).
// Per phase in-flight = 2 A-loads + 9 B-DMA = 11; publish = WAITVL(11)+BAR.
// ===========================================================================
#define AB2 2048
#define BB2 18432

__global__ __launch_bounds__(256, 2) void fused_cell7(
    const float* __restrict__ p,   const float* __restrict__ h,
    const float* __restrict__ c_h, const float* __restrict__ g_t,
    const float* __restrict__ c_g_t, const float* __restrict__ g_s,
    const float* __restrict__ c_g_s,
    const u16* __restrict__ WT0, const float* __restrict__ Bias,
    float* __restrict__ h_new, float* __restrict__ c_h_new)
{
    extern __shared__ u16 smem[];   // [A0|A1|B0|B1]

    const int tid = threadIdx.x;
    const int lin = blockIdx.x;
    const int xcd = lin & 7, j = lin >> 3;
    const int mtile = j % 13;
    const int slab  = (j / 13) * 8 + xcd;   // 0..95
    const int ntile = slab & 3, n = slab >> 2;

    const int s_r = tid >> 2, s_c = tid & 3;
    const int gr  = mtile * 64 + s_r;
    const bool mval = (gr < MR);
    const int ec = (gr * NN + n) * 256;
    const bool vnb = (n > 0), vna = (n < NN - 1), vtp = (gr % TT) != 0;

    const int wro = s_r * 32 + ((s_c ^ ((s_r >> 1) & 3)) << 3);

    const int wave = tid >> 6, lane = tid & 63;
    const int lrow = lane & 15, lci = lane >> 4;

    int aro[4];
    #pragma unroll
    for (int m = 0; m < 4; ++m) {
        const int row = m * 16 + lrow;
        aro[m] = row * 32 + ((lci ^ ((row >> 1) & 3)) << 3);
    }
    const int colr = wave * 16 + lrow;
    const int bro  = colr * 32 + ((lci ^ ((colr >> 1) & 3)) << 3);

    const u16* wbase = WT0 + (size_t)n * 458752 + (size_t)(ntile * 64) * 32 + wro;

    f32x4 acc[9][4];
    #pragma unroll
    for (int g = 0; g < 9; ++g)
        #pragma unroll
        for (int m = 0; m < 4; ++m) acc[g][m] = f32x4{0.f, 0.f, 0.f, 0.f};

    float4 aOlo, aOhi, aNlo, aNhi;

    auto loadA = [&](int kt, float4& lo, float4& hi) {
        const int K0 = kt * 32, seg = K0 >> 8, koff = (K0 & 255) + s_c * 8;
        const float* src = nullptr; bool valid = mval;
        switch (seg) {
            case 0: src = p + ec + koff; break;
            case 1: valid &= vnb; src = h + ec - 256 + koff; break;
            case 2: src = h + ec + koff; break;
            case 3: valid &= vna; src = h + ec + 256 + koff; break;
            case 4: valid &= vtp; src = h + ec - NN * 256 + koff; break;
            case 5: src = g_t + ec + koff; break;
            default: src = g_s + ec + koff; break;
        }
        lo = make_float4(0.f, 0.f, 0.f, 0.f); hi = lo;
        if (valid) { lo = *(const float4*)src; hi = *(const float4*)(src + 4); }
    };
    auto storeA = [&](int buf, const float4& lo, const float4& hi) {
        u16x8 aw;
        aw[0] = f2b(lo.x); aw[1] = f2b(lo.y); aw[2] = f2b(lo.z); aw[3] = f2b(lo.w);
        aw[4] = f2b(hi.x); aw[5] = f2b(hi.y); aw[6] = f2b(hi.z); aw[7] = f2b(hi.w);
        *(u16x8*)(&smem[buf * AB2 + wro]) = aw;
    };
    auto dmaB = [&](int kt, int buf) {
        const u16* wb = wbase + (size_t)kt * 8192;
        u16* dst = &smem[2 * AB2 + buf * BB2 + tid * 8];
        #pragma unroll
        for (int g = 0; g < 9; ++g)
            gld16(wb + (size_t)g * 11010048, dst + g * 2048);
    };
    auto domfma = [&](int buf) {
        const u16* Asb = smem + buf * AB2;
        const u16* Bsb = smem + 2 * AB2 + buf * BB2;
        s16x8 af[4];
        #pragma unroll
        for (int m = 0; m < 4; ++m) af[m] = *(const s16x8*)(&Asb[aro[m]]);
        __builtin_amdgcn_s_setprio(1);
        #pragma unroll
        for (int g = 0; g < 9; ++g) {
            const s16x8 bf = *(const s16x8*)(&Bsb[g * 2048 + bro]);
            #pragma unroll
            for (int m = 0; m < 4; ++m)
                acc[g][m] = __builtin_amdgcn_mfma_f32_16x16x32_bf16(af[m], bf, acc[g][m], 0, 0, 0);
        }
        __builtin_amdgcn_s_setprio(0);
    };

    // prologue: publish buf0 (tile 0); leave A(1)+B(1) (11) in flight
    loadA(0, aOlo, aOhi);
    dmaB(0, 0);
    storeA(0, aOlo, aOhi);            // auto-wait drains A(0) only
    loadA(1, aOlo, aOhi);
    dmaB(1, 1);
    WAITVL(11); BAR();                // B(0) done + A(0) ds_write drained

    for (int kt = 0; kt < 54; kt += 2) {
        domfma(0);                    // tile kt
        BAR();                        // readers done with buf0
        loadA(kt + 2, aNlo, aNhi);
        dmaB(kt + 2, 0);
        storeA(1, aOlo, aOhi);        // A(kt+1): auto vmcnt(20)
        WAITVL(11); BAR();            // publish buf1 = tile kt+1
        domfma(1);                    // tile kt+1
        BAR();                        // readers done with buf1
        loadA(kt + 3, aOlo, aOhi);
        dmaB(kt + 3, 1);
        storeA(0, aNlo, aNhi);        // A(kt+2)
        WAITVL(11); BAR();            // publish buf0 = tile kt+2
    }
    domfma(0);                        // tile 54
    BAR();
    storeA(1, aOlo, aOhi);            // A(55)
    WAITVL(0); BAR();                 // publish buf1 = tile 55
    domfma(1);                        // tile 55

    // ---- epilogue: bias + cell update, f32 stores
    const int col = ntile * 64 + wave * 16 + lrow;
    float bv[9];
    #pragma unroll
    for (int g = 0; g < 9; ++g) bv[g] = Bias[(g * NN + n) * 256 + col];

    #pragma unroll
    for (int m = 0; m < 4; ++m) {
        #pragma unroll
        for (int i = 0; i < 4; ++i) {
            const int row = mtile * 64 + m * 16 + (lane >> 4) * 4 + i;
            if (row < MR) {
                const size_t e = ((size_t)(row * NN + n)) * 256 + col;
                const float i_n  = sig_(acc[0][m][i] + bv[0]);
                const float f_lt = sig_(acc[1][m][i] + bv[1]);
                const float f_ft = sig_(acc[2][m][i] + bv[2]);
                const float f_rt = sig_(acc[3][m][i] + bv[3]);
                const float f_s  = sig_(acc[4][m][i] + bv[4]);
                const float f_gt = sig_(acc[5][m][i] + bv[5]);
                const float f_gs = sig_(acc[6][m][i] + bv[6]);
                const float o_n  = sig_(acc[7][m][i] + bv[7]);
                const float c_n  = tanh_(acc[8][m][i] + bv[8]);
                const float cb = (n > 0)      ? c_h[e - 256] : 0.f;
                const float ca = (n < NN - 1) ? c_h[e + 256] : 0.f;
                const float cs = (row % TT)   ? c_h[e - NN * 256] : 0.f;
                const float cn = f_lt * cb + f_ft * c_h[e] + f_rt * ca
                               + f_s * cs + f_gt * c_g_t[e] + f_gs * c_g_s[e]
                               + i_n * c_n;
                c_h_new[e] = cn;
                h_new[e]   = o_n * tanh_(cn);
            }
        }
    }
}

// ===========================================================================
// Phase 1: counted-vmcnt pipeline + T14 split A-staging (unchanged from r10).
// ===========================================================================
__global__ __launch_bounds__(256, 4) void fused_global5(
    const float* __restrict__ hn,   const float* __restrict__ g_t,
    const float* __restrict__ g_s,  const float* __restrict__ c_g_t,
    const float* __restrict__ c_g_s,
    const u16* __restrict__ WT1, const float* __restrict__ Bg,
    float* __restrict__ out2, float* __restrict__ out3,
    float* __restrict__ out4, float* __restrict__ out5)
{
    __shared__ u16 smem[2 * 2048 + 2 * 6144];

    const int tid = threadIdx.x;
    const int lin = blockIdx.x;
    const int xcd = lin & 7, j = lin >> 3;
    const int mtile = j % 13;
    const int slab  = (j / 13) * 8 + xcd;   // 0..191
    const int ntile = slab & 3;
    const int zz    = slab >> 2;            // 0..47
    const int n = zz % NN, grp = zz / NN;

    const float* xg = grp ? g_s : g_t;
    const float* cg = grp ? c_g_s : c_g_t;
    float* og  = grp ? out4 : out2;
    float* ocg = grp ? out5 : out3;

    const int s_r = tid >> 2, s_c = tid & 3;
    const int gr  = mtile * 64 + s_r;
    const bool mval = (gr < MR);
    const int ec = (gr * NN + n) * 256;

    const int wro = s_r * 32 + ((s_c ^ ((s_r >> 1) & 3)) << 3);

    const int wave = tid >> 6, lane = tid & 63;
    const int lrow = lane & 15, lci = lane >> 4;

    int aro[4];
    #pragma unroll
    for (int m = 0; m < 4; ++m) {
        const int row = m * 16 + lrow;
        aro[m] = row * 32 + ((lci ^ ((row >> 1) & 3)) << 3);
    }
    const int colr = wave * 16 + lrow;
    const int bro  = colr * 32 + ((lci ^ ((colr >> 1) & 3)) << 3);

    const u16* wbase = WT1 + (size_t)(grp * 3 * NN + n) * 131072
                           + (size_t)(ntile * 64) * 32 + wro;

    f32x4 acc[3][4];
    #pragma unroll
    for (int g = 0; g < 3; ++g)
        #pragma unroll
        for (int m = 0; m < 4; ++m) acc[g][m] = f32x4{0.f, 0.f, 0.f, 0.f};

    float4 aOlo, aOhi, aNlo, aNhi;

    auto loadA = [&](int kt, float4& lo, float4& hi) {
        const int K0 = kt * 32, koff = (K0 & 255) + s_c * 8;
        const float* src = ((K0 < 256) ? hn : xg) + ec + koff;
        lo = make_float4(0.f, 0.f, 0.f, 0.f); hi = lo;
        if (mval) { lo = *(const float4*)src; hi = *(const float4*)(src + 4); }
    };
    auto storeA = [&](int buf, const float4& lo, const float4& hi) {
        u16x8 aw;
        aw[0] = f2b(lo.x); aw[1] = f2b(lo.y); aw[2] = f2b(lo.z); aw[3] = f2b(lo.w);
        aw[4] = f2b(hi.x); aw[5] = f2b(hi.y); aw[6] = f2b(hi.z); aw[7] = f2b(hi.w);
        *(u16x8*)(&smem[buf * 2048 + wro]) = aw;
    };
    auto dmaB = [&](int kt, int buf) {
        const u16* wb = wbase + (size_t)kt * 8192;
        u16* dst = &smem[2 * 2048 + buf * 6144 + tid * 8];
        #pragma unroll
        for (int g = 0; g < 3; ++g)
            gld16(wb + (size_t)g * 3145728, dst + g * 2048);
    };
    auto domfma = [&](int buf) {
        const u16* Asb = smem + buf * 2048;
        const u16* Bsb = smem + 2 * 2048 + buf * 6144;
        s16x8 af[4];
        #pragma unroll
        for (int m = 0; m < 4; ++m) af[m] = *(const s16x8*)(&Asb[aro[m]]);
        __builtin_amdgcn_s_setprio(1);
        #pragma unroll
        for (int g = 0; g < 3; ++g) {
            const s16x8 bf = *(const s16x8*)(&Bsb[g * 2048 + bro]);
            #pragma unroll
            for (int m = 0; m < 4; ++m)
                acc[g][m] = __builtin_amdgcn_mfma_f32_16x16x32_bf16(af[m], bf, acc[g][m], 0, 0, 0);
        }
        __builtin_amdgcn_s_setprio(0);
    };

    loadA(0, aOlo, aOhi);
    dmaB(0, 0);
    storeA(0, aOlo, aOhi);
    loadA(1, aOlo, aOhi);
    dmaB(1, 1);
    WAITVL(5); BAR();
    for (int kt = 0; kt < 14; kt += 2) {
        domfma(0);
        BAR();
        loadA(kt + 2, aNlo, aNhi);
        dmaB(kt + 2, 0);
        storeA(1, aOlo, aOhi);
        WAITVL(5); BAR();
        domfma(1);
        BAR();
        loadA(kt + 3, aOlo, aOhi);
        dmaB(kt + 3, 1);
        storeA(0, aNlo, aNhi);
        WAITVL(5); BAR();
    }
    domfma(0);
    BAR();
    storeA(1, aOlo, aOhi);
    WAITVL(0); BAR();
    domfma(1);

    const int col = ntile * 64 + wave * 16 + lrow;
    float bv[3];
    #pragma unroll
    for (int g = 0; g < 3; ++g) bv[g] = Bg[((grp * 3 + g) * NN + n) * 256 + col];

    #pragma unroll
    for (int m = 0; m < 4; ++m) {
        #pragma unroll
        for (int i = 0; i < 4; ++i) {
            const int row = mtile * 64 + m * 16 + (lane >> 4) * 4 + i;
            if (row < MR) {
                const size_t e = ((size_t)(row * NN + n)) * 256 + col;
                const float f    = sig_(acc[0][m][i] + bv[0]);
                const float cand = tanh_(acc[1][m][i] + bv[1]);
                const float o    = sig_(acc[2][m][i] + bv[2]);
                const float cn = f * cg[e] + (1.f - f) * cand;
                ocg[e] = cn;
                og[e]  = o * tanh_(cn);
            }
        }
    }
}

extern "C" void kernel_launch(void* const* d_in, const int* in_sizes, int n_in,
                              void* d_out, int out_size, void* d_ws, size_t ws_size,
                              hipStream_t stream)
{
    const float* h     = (const float*)d_in[0];
    const float* c_h   = (const float*)d_in[1];
    const float* p     = (const float*)d_in[2];
    const float* g_t   = (const float*)d_in[3];
    const float* c_g_t = (const float*)d_in[4];
    const float* g_s   = (const float*)d_in[5];
    const float* c_g_s = (const float*)d_in[6];
    const float* U     = (const float*)d_in[7];
    const float* Wt    = (const float*)d_in[8];
    const float* Ws    = (const float*)d_in[9];
    const float* Zt    = (const float*)d_in[10];
    const float* Zs    = (const float*)d_in[11];
    const float* bb    = (const float*)d_in[12];
    const float* Wg    = (const float*)d_in[13];
    const float* Zg    = (const float*)d_in[14];
    const float* bg    = (const float*)d_in[15];

    float* out0 = (float*)d_out;        // h_new
    float* out1 = out0 + (size_t)SZT;   // c_h_new
    float* out2 = out1 + (size_t)SZT;   // g_t_new
    float* out3 = out2 + (size_t)SZT;   // c_g_t_new
    float* out4 = out3 + (size_t)SZT;   // g_s_new
    float* out5 = out4 + (size_t)SZT;   // c_g_s_new

    u16* wt0 = (u16*)d_ws;
    u16* wt1 = wt0 + WT0_ELEMS;

    dim3 blk(256);
    prep_w<<<dim3(28800), blk, 0, stream>>>(U, Wt, Ws, Zt, Zs, Wg, Zg, wt0, wt1);

    hipFuncSetAttribute((const void*)fused_cell7,
                        hipFuncAttributeMaxDynamicSharedMemorySize, 81920);
    fused_cell7<<<dim3(1248), blk, 81920, stream>>>(
        p, h, c_h, g_t, c_g_t, g_s, c_g_s, wt0, bb, out0, out1);
    fused_global5<<<dim3(2496), blk, 0, stream>>>(
        out0, g_t, g_s, c_g_t, c_g_s, wt1, bg, out2, out3, out4, out5);
}

// Round 12
// 470.388 us; speedup vs baseline: 1.0902x; 1.0902x over previous
//
#include <hip/hip_runtime.h>
#include <hip/hip_bf16.h>

typedef unsigned short u16;
typedef u16 u16x8 __attribute__((ext_vector_type(8)));
typedef short s16x8 __attribute__((ext_vector_type(8)));
typedef float f32x4 __attribute__((ext_vector_type(4)));
typedef unsigned int u32;

#define NN 24
#define TT 49
#define MR 784                  // B*T = 16*49
#define SZT 4816896             // B*T*N*H

__device__ inline u16 f2b(float f){
    __hip_bfloat16 b = __float2bfloat16(f); u16 r; __builtin_memcpy(&r, &b, 2); return r;
}
__device__ inline float sig_(float x){ return 1.f / (1.f + __expf(-x)); }
__device__ inline float tanh_(float x){ float e = __expf(2.f * x); return (e - 1.f) / (e + 1.f); }

__device__ inline void gld16(const u16* g, u16* l){
    __builtin_amdgcn_global_load_lds(
        (const __attribute__((address_space(1))) unsigned int*)g,
        (__attribute__((address_space(3))) unsigned int*)l, 16, 0, 0);
}

#define BAR()      __builtin_amdgcn_s_barrier()
#define WAITVM(N)  asm volatile("s_waitcnt vmcnt(" #N ")" ::: "memory")
#define WAITVL(N)  asm volatile("s_waitcnt vmcnt(" #N ") lgkmcnt(0)" ::: "memory")

// ws layout: WT0 bf16 [216][56][256][32] | WT1 bf16 [144][16][256][32] | Abf bf16 [24][56][784][32]
#define WT0_ELEMS ((size_t)216 * 256 * 1792)
#define WT1_ELEMS ((size_t)144 * 256 * 512)

// ===========================================================================
// Merged prepass: wprep0 (24192 blk) | wprep1 (4608 blk) | aprep (17472 blk)
// ===========================================================================
__global__ __launch_bounds__(256) void prep_all(
    const float* __restrict__ U,  const float* __restrict__ Wt,
    const float* __restrict__ Ws, const float* __restrict__ Zt,
    const float* __restrict__ Zs, const float* __restrict__ Wg,
    const float* __restrict__ Zg,
    const float* __restrict__ p,  const float* __restrict__ h,
    const float* __restrict__ g_t, const float* __restrict__ g_s,
    u16* __restrict__ wt0, u16* __restrict__ wt1, u16* __restrict__ Abf)
{
    __shared__ u16 T[64][72];
    const int tid = threadIdx.x;
    const int lin = blockIdx.x;

    if (lin < 24192) {
        const int kt = lin % 28, ct = (lin / 28) % 4, z = lin / 112;
        const int n = z % NN, g = z / NN;
        const int k0 = kt * 64;
        const float* wbase;
        if (k0 < 256)       wbase = U  + (size_t)((g * NN + n) * 256 + k0)          * 256;
        else if (k0 < 1024) wbase = Wt + (size_t)((g * NN + n) * 768 + (k0 - 256))  * 256;
        else if (k0 < 1280) wbase = Ws + (size_t)((g * NN + n) * 256 + (k0 - 1024)) * 256;
        else if (k0 < 1536) wbase = Zt + (size_t)((g * NN + n) * 256 + (k0 - 1280)) * 256;
        else { const int g2 = (g == 2) ? 1 : g;      // Zs_eff: f_ft uses Zs[lt]
               wbase = Zs + (size_t)((g2 * NN + n) * 256 + (k0 - 1536)) * 256; }
        const int colg = ct * 64 + (tid & 15) * 4;
        #pragma unroll
        for (int it = 0; it < 4; ++it) {
            const int krl = (tid >> 4) + it * 16;
            const float4 v = *(const float4*)(wbase + (size_t)krl * 256 + colg);
            const int cl = (tid & 15) * 4;
            T[cl + 0][krl] = f2b(v.x); T[cl + 1][krl] = f2b(v.y);
            T[cl + 2][krl] = f2b(v.z); T[cl + 3][krl] = f2b(v.w);
        }
        __syncthreads();
        const int col_l = tid >> 2, ks = (tid & 3) * 16;
        const int ktile = 2 * kt + (ks >> 5);
        const int koff  = ks & 31;
        u16* dst = wt0 + (size_t)z * 458752 + (size_t)ktile * 8192
                       + (size_t)(ct * 64 + col_l) * 32 + koff;
        u16x8 w0, w1;
        #pragma unroll
        for (int j2 = 0; j2 < 8; ++j2) { w0[j2] = T[col_l][ks + j2]; w1[j2] = T[col_l][ks + 8 + j2]; }
        *(u16x8*)(dst) = w0; *(u16x8*)(dst + 8) = w1;
    } else if (lin < 28800) {
        const int l = lin - 24192;
        const int kt = l % 8, ct = (l / 8) % 4, z = l / 32;
        const int k0 = kt * 64;
        const float* wbase = (k0 < 256)
            ? Wg + (size_t)(z * 256 + k0) * 256
            : Zg + (size_t)(z * 256 + (k0 - 256)) * 256;
        const int colg = ct * 64 + (tid & 15) * 4;
        #pragma unroll
        for (int it = 0; it < 4; ++it) {
            const int krl = (tid >> 4) + it * 16;
            const float4 v = *(const float4*)(wbase + (size_t)krl * 256 + colg);
            const int cl = (tid & 15) * 4;
            T[cl + 0][krl] = f2b(v.x); T[cl + 1][krl] = f2b(v.y);
            T[cl + 2][krl] = f2b(v.z); T[cl + 3][krl] = f2b(v.w);
        }
        __syncthreads();
        const int col_l = tid >> 2, ks = (tid & 3) * 16;
        const int ktile = 2 * kt + (ks >> 5);
        const int koff  = ks & 31;
        u16* dst = wt1 + (size_t)z * 131072 + (size_t)ktile * 8192
                       + (size_t)(ct * 64 + col_l) * 32 + koff;
        u16x8 w0, w1;
        #pragma unroll
        for (int j2 = 0; j2 < 8; ++j2) { w0[j2] = T[col_l][ks + j2]; w1[j2] = T[col_l][ks + 8 + j2]; }
        *(u16x8*)(dst) = w0; *(u16x8*)(dst + 8) = w1;
    } else {
        const int l = lin - 28800;
        const int bx = l % 13, kt = (l / 13) % 56, n = l / 728;
        const int row = bx * 64 + (tid >> 2);
        if (row >= MR) return;
        const int c  = tid & 3;
        const int kg = kt * 32 + c * 8;
        const int seg = kg >> 8, koff = kg & 255;
        const int ec = (row * NN + n) * 256 + koff;
        const float* src = nullptr; bool valid = true;
        switch (seg) {
            case 0: src = p + ec; break;
            case 1: valid = (n > 0);          src = h + ec - 256; break;
            case 2: src = h + ec; break;
            case 3: valid = (n < NN - 1);     src = h + ec + 256; break;
            case 4: valid = (row % TT) != 0;  src = h + ec - NN * 256; break;
            case 5: src = g_t + ec; break;
            default: src = g_s + ec; break;
        }
        float4 lo = {0.f,0.f,0.f,0.f}, hi = lo;
        if (valid) { lo = *(const float4*)src; hi = *(const float4*)(src + 4); }
        u16x8 w;
        w[0] = f2b(lo.x); w[1] = f2b(lo.y); w[2] = f2b(lo.z); w[3] = f2b(lo.w);
        w[4] = f2b(hi.x); w[5] = f2b(hi.y); w[6] = f2b(hi.z); w[7] = f2b(hi.w);
        *(u16x8*)(Abf + ((size_t)(n * 56 + kt) * MR + row) * 32 + c * 8) = w;
    }
}

// ===========================================================================
// Phase 0: 128x64 tile, 8 waves (rh,cq), pure-DMA K-loop, counted vmcnt.
// Per wave per phase: 1 A-granule + {5|4} B-granules; publish vmcnt({6|5}).
// LDS: A dbuf 2x4096 elems + B dbuf 2x18432 elems = 90112 B. 1 block/CU.
// ===========================================================================
#define AB8 4096
#define BB8 18432

__global__ __launch_bounds__(512, 1) void fused_cell8(
    const float* __restrict__ c_h, const float* __restrict__ c_g_t,
    const float* __restrict__ c_g_s,
    const u16* __restrict__ Abf, const u16* __restrict__ WT0,
    const float* __restrict__ Bias,
    float* __restrict__ h_new, float* __restrict__ c_h_new)
{
    extern __shared__ u16 smem[];   // [A0|A1|B0|B1]

    const int tid = threadIdx.x;
    const int lin = blockIdx.x;
    const int xcd = lin & 7, j = lin >> 3;
    const int mtile = j % 7;                 // 128-row tiles, 7 per slab
    const int slab  = (j / 7) * 8 + xcd;     // 0..95
    const int ntile = slab & 3, n = slab >> 2;

    const int wave = tid >> 6, lane = tid & 63;
    const int rh = wave >> 2, cq = wave & 3;
    const int lrow = lane & 15, lci = lane >> 4;

    // ---- DMA source/dest precompute (per-lane, kt-invariant parts)
    const int rloc = wave * 16 + (lane >> 2);            // LDS A row 0..127
    const int rglb = mtile * 128 + rloc;
    const int rsrc = (rglb < MR) ? rglb : (MR - 1);      // clamp (discarded rows)
    const int ach  = (lane & 3) ^ ((rloc >> 1) & 3);
    const u16* aSrc = Abf + ((size_t)(n * 56) * MR + rsrc) * 32 + ach * 8;
    const int aDst = wave * 512 + lane * 8;

    const int g0 = (wave < 4) ? wave * 5 : 20 + (wave - 4) * 4;
    const int ng = (wave < 4) ? 5 : 4;
    const u16* bSrc[5]; int bDst[5];
    #pragma unroll
    for (int i = 0; i < 5; ++i) {
        const int G = g0 + ((i < ng) ? i : 0);
        const int g = G >> 2, q = G & 3;
        const int c = q * 16 + (lane >> 2);              // col 0..63
        const int ch = (lane & 3) ^ ((c >> 1) & 3);
        bSrc[i] = WT0 + (size_t)n * 458752 + (size_t)g * 11010048
                + (size_t)(ntile * 64 + c) * 32 + ch * 8;
        bDst[i] = g * 2048 + q * 512 + lane * 8;
    }

    // ---- fragment read offsets (XOR matches write-side pre-swizzle)
    int aro[4];
    #pragma unroll
    for (int m = 0; m < 4; ++m) {
        const int row = rh * 64 + m * 16 + lrow;
        aro[m] = row * 32 + ((lci ^ ((row >> 1) & 3)) << 3);
    }
    const int colr = cq * 16 + lrow;
    const int bro  = colr * 32 + ((lci ^ ((colr >> 1) & 3)) << 3);

    f32x4 acc[9][4];
    #pragma unroll
    for (int g = 0; g < 9; ++g)
        #pragma unroll
        for (int m = 0; m < 4; ++m) acc[g][m] = f32x4{0.f, 0.f, 0.f, 0.f};

    auto dma = [&](int kt, int buf) {
        gld16(aSrc + (size_t)kt * (MR * 32), &smem[buf * AB8 + aDst]);
        const size_t ko = (size_t)kt * 8192;
        u16* bBase = &smem[2 * AB8 + buf * BB8];
        #pragma unroll
        for (int i = 0; i < 5; ++i)
            if (i < ng) gld16(bSrc[i] + ko, bBase + bDst[i]);
    };
    auto publish = [&]() {
        if (wave < 4) { WAITVM(6); } else { WAITVM(5); }
        BAR();
    };
    auto domfma = [&](int buf) {
        const u16* Asb = smem + buf * AB8;
        const u16* Bsb = smem + 2 * AB8 + buf * BB8;
        s16x8 af[4];
        #pragma unroll
        for (int m = 0; m < 4; ++m) af[m] = *(const s16x8*)(&Asb[aro[m]]);
        __builtin_amdgcn_s_setprio(1);
        #pragma unroll
        for (int g = 0; g < 9; ++g) {
            const s16x8 bf = *(const s16x8*)(&Bsb[g * 2048 + bro]);
            #pragma unroll
            for (int m = 0; m < 4; ++m)
                acc[g][m] = __builtin_amdgcn_mfma_f32_16x16x32_bf16(af[m], bf, acc[g][m], 0, 0, 0);
        }
        __builtin_amdgcn_s_setprio(0);
    };

    // prologue
    dma(0, 0);
    WAITVM(0); BAR();
    dma(1, 1);
    for (int kt = 0; kt < 54; kt += 2) {
        domfma(0);                    // tile kt
        BAR();                        // readers done with buf0
        dma(kt + 2, 0);
        publish();                    // tile kt+1 ready; kt+2 in flight
        domfma(1);                    // tile kt+1
        BAR();                        // readers done with buf1
        dma(kt + 3, 1);
        publish();                    // tile kt+2 ready
    }
    domfma(0);                        // tile 54
    BAR();
    WAITVM(0); BAR();                 // tile 55 ready
    domfma(1);                        // tile 55

    // ---- epilogue: bias + cell update, f32 stores
    const int col = ntile * 64 + cq * 16 + lrow;
    float bv[9];
    #pragma unroll
    for (int g = 0; g < 9; ++g) bv[g] = Bias[(g * NN + n) * 256 + col];

    #pragma unroll
    for (int m = 0; m < 4; ++m) {
        #pragma unroll
        for (int i = 0; i < 4; ++i) {
            const int row = mtile * 128 + rh * 64 + m * 16 + (lane >> 4) * 4 + i;
            if (row < MR) {
                const size_t e = ((size_t)(row * NN + n)) * 256 + col;
                const float i_n  = sig_(acc[0][m][i] + bv[0]);
                const float f_lt = sig_(acc[1][m][i] + bv[1]);
                const float f_ft = sig_(acc[2][m][i] + bv[2]);
                const float f_rt = sig_(acc[3][m][i] + bv[3]);
                const float f_s  = sig_(acc[4][m][i] + bv[4]);
                const float f_gt = sig_(acc[5][m][i] + bv[5]);
                const float f_gs = sig_(acc[6][m][i] + bv[6]);
                const float o_n  = sig_(acc[7][m][i] + bv[7]);
                const float c_n  = tanh_(acc[8][m][i] + bv[8]);
                const float cb = (n > 0)      ? c_h[e - 256] : 0.f;
                const float ca = (n < NN - 1) ? c_h[e + 256] : 0.f;
                const float cs = (row % TT)   ? c_h[e - NN * 256] : 0.f;
                const float cn = f_lt * cb + f_ft * c_h[e] + f_rt * ca
                               + f_s * cs + f_gt * c_g_t[e] + f_gs * c_g_s[e]
                               + i_n * c_n;
                c_h_new[e] = cn;
                h_new[e]   = o_n * tanh_(cn);
            }
        }
    }
}

// ===========================================================================
// Phase 1: counted-vmcnt pipeline + T14 split A-staging (r10, unchanged).
// ===========================================================================
__global__ __launch_bounds__(256, 4) void fused_global5(
    const float* __restrict__ hn,   const float* __restrict__ g_t,
    const float* __restrict__ g_s,  const float* __restrict__ c_g_t,
    const float* __restrict__ c_g_s,
    const u16* __restrict__ WT1, const float* __restrict__ Bg,
    float* __restrict__ out2, float* __restrict__ out3,
    float* __restrict__ out4, float* __restrict__ out5)
{
    __shared__ u16 smem[2 * 2048 + 2 * 6144];

    const int tid = threadIdx.x;
    const int lin = blockIdx.x;
    const int xcd = lin & 7, j = lin >> 3;
    const int mtile = j % 13;
    const int slab  = (j / 13) * 8 + xcd;   // 0..191
    const int ntile = slab & 3;
    const int zz    = slab >> 2;            // 0..47
    const int n = zz % NN, grp = zz / NN;

    const float* xg = grp ? g_s : g_t;
    const float* cg = grp ? c_g_s : c_g_t;
    float* og  = grp ? out4 : out2;
    float* ocg = grp ? out5 : out3;

    const int s_r = tid >> 2, s_c = tid & 3;
    const int gr  = mtile * 64 + s_r;
    const bool mval = (gr < MR);
    const int ec = (gr * NN + n) * 256;

    const int wro = s_r * 32 + ((s_c ^ ((s_r >> 1) & 3)) << 3);

    const int wave = tid >> 6, lane = tid & 63;
    const int lrow = lane & 15, lci = lane >> 4;

    int aro[4];
    #pragma unroll
    for (int m = 0; m < 4; ++m) {
        const int row = m * 16 + lrow;
        aro[m] = row * 32 + ((lci ^ ((row >> 1) & 3)) << 3);
    }
    const int colr = wave * 16 + lrow;
    const int bro  = colr * 32 + ((lci ^ ((colr >> 1) & 3)) << 3);

    const u16* wbase = WT1 + (size_t)(grp * 3 * NN + n) * 131072
                           + (size_t)(ntile * 64) * 32 + wro;

    f32x4 acc[3][4];
    #pragma unroll
    for (int g = 0; g < 3; ++g)
        #pragma unroll
        for (int m = 0; m < 4; ++m) acc[g][m] = f32x4{0.f, 0.f, 0.f, 0.f};

    float4 aOlo, aOhi, aNlo, aNhi;

    auto loadA = [&](int kt, float4& lo, float4& hi) {
        const int K0 = kt * 32, koff = (K0 & 255) + s_c * 8;
        const float* src = ((K0 < 256) ? hn : xg) + ec + koff;
        lo = make_float4(0.f, 0.f, 0.f, 0.f); hi = lo;
        if (mval) { lo = *(const float4*)src; hi = *(const float4*)(src + 4); }
    };
    auto storeA = [&](int buf, const float4& lo, const float4& hi) {
        u16x8 aw;
        aw[0] = f2b(lo.x); aw[1] = f2b(lo.y); aw[2] = f2b(lo.z); aw[3] = f2b(lo.w);
        aw[4] = f2b(hi.x); aw[5] = f2b(hi.y); aw[6] = f2b(hi.z); aw[7] = f2b(hi.w);
        *(u16x8*)(&smem[buf * 2048 + wro]) = aw;
    };
    auto dmaB = [&](int kt, int buf) {
        const u16* wb = wbase + (size_t)kt * 8192;
        u16* dst = &smem[2 * 2048 + buf * 6144 + tid * 8];
        #pragma unroll
        for (int g = 0; g < 3; ++g)
            gld16(wb + (size_t)g * 3145728, dst + g * 2048);
    };
    auto domfma = [&](int buf) {
        const u16* Asb = smem + buf * 2048;
        const u16* Bsb = smem + 2 * 2048 + buf * 6144;
        s16x8 af[4];
        #pragma unroll
        for (int m = 0; m < 4; ++m) af[m] = *(const s16x8*)(&Asb[aro[m]]);
        __builtin_amdgcn_s_setprio(1);
        #pragma unroll
        for (int g = 0; g < 3; ++g) {
            const s16x8 bf = *(const s16x8*)(&Bsb[g * 2048 + bro]);
            #pragma unroll
            for (int m = 0; m < 4; ++m)
                acc[g][m] = __builtin_amdgcn_mfma_f32_16x16x32_bf16(af[m], bf, acc[g][m], 0, 0, 0);
        }
        __builtin_amdgcn_s_setprio(0);
    };

    loadA(0, aOlo, aOhi);
    dmaB(0, 0);
    storeA(0, aOlo, aOhi);
    loadA(1, aOlo, aOhi);
    dmaB(1, 1);
    WAITVL(5); BAR();
    for (int kt = 0; kt < 14; kt += 2) {
        domfma(0);
        BAR();
        loadA(kt + 2, aNlo, aNhi);
        dmaB(kt + 2, 0);
        storeA(1, aOlo, aOhi);
        WAITVL(5); BAR();
        domfma(1);
        BAR();
        loadA(kt + 3, aOlo, aOhi);
        dmaB(kt + 3, 1);
        storeA(0, aNlo, aNhi);
        WAITVL(5); BAR();
    }
    domfma(0);
    BAR();
    storeA(1, aOlo, aOhi);
    WAITVL(0); BAR();
    domfma(1);

    const int col = ntile * 64 + wave * 16 + lrow;
    float bv[3];
    #pragma unroll
    for (int g = 0; g < 3; ++g) bv[g] = Bg[((grp * 3 + g) * NN + n) * 256 + col];

    #pragma unroll
    for (int m = 0; m < 4; ++m) {
        #pragma unroll
        for (int i = 0; i < 4; ++i) {
            const int row = mtile * 64 + m * 16 + (lane >> 4) * 4 + i;
            if (row < MR) {
                const size_t e = ((size_t)(row * NN + n)) * 256 + col;
                const float f    = sig_(acc[0][m][i] + bv[0]);
                const float cand = tanh_(acc[1][m][i] + bv[1]);
                const float o    = sig_(acc[2][m][i] + bv[2]);
                const float cn = f * cg[e] + (1.f - f) * cand;
                ocg[e] = cn;
                og[e]  = o * tanh_(cn);
            }
        }
    }
}

extern "C" void kernel_launch(void* const* d_in, const int* in_sizes, int n_in,
                              void* d_out, int out_size, void* d_ws, size_t ws_size,
                              hipStream_t stream)
{
    const float* h     = (const float*)d_in[0];
    const float* c_h   = (const float*)d_in[1];
    const float* p     = (const float*)d_in[2];
    const float* g_t   = (const float*)d_in[3];
    const float* c_g_t = (const float*)d_in[4];
    const float* g_s   = (const float*)d_in[5];
    const float* c_g_s = (const float*)d_in[6];
    const float* U     = (const float*)d_in[7];
    const float* Wt    = (const float*)d_in[8];
    const float* Ws    = (const float*)d_in[9];
    const float* Zt    = (const float*)d_in[10];
    const float* Zs    = (const float*)d_in[11];
    const float* bb    = (const float*)d_in[12];
    const float* Wg    = (const float*)d_in[13];
    const float* Zg    = (const float*)d_in[14];
    const float* bg    = (const float*)d_in[15];

    float* out0 = (float*)d_out;        // h_new
    float* out1 = out0 + (size_t)SZT;   // c_h_new
    float* out2 = out1 + (size_t)SZT;   // g_t_new
    float* out3 = out2 + (size_t)SZT;   // c_g_t_new
    float* out4 = out3 + (size_t)SZT;   // g_s_new
    float* out5 = out4 + (size_t)SZT;   // c_g_s_new

    u16* wt0 = (u16*)d_ws;
    u16* wt1 = wt0 + WT0_ELEMS;
    u16* abf = wt1 + WT1_ELEMS;

    dim3 blk(256);
    prep_all<<<dim3(46272), blk, 0, stream>>>(U, Wt, Ws, Zt, Zs, Wg, Zg,
                                              p, h, g_t, g_s, wt0, wt1, abf);

    hipFuncSetAttribute((const void*)fused_cell8,
                        hipFuncAttributeMaxDynamicSharedMemorySize, 90112);
    fused_cell8<<<dim3(672), dim3(512), 90112, stream>>>(
        c_h, c_g_t, c_g_s, abf, wt0, bb, out0, out1);
    fused_global5<<<dim3(2496), blk, 0, stream>>>(
        out0, g_t, g_s, c_g_t, c_g_s, wt1, bg, out2, out3, out4, out5);
}

// Round 14
// 452.528 us; speedup vs baseline: 1.1332x; 1.0395x over previous
//
#include <hip/hip_runtime.h>
#include <hip/hip_bf16.h>

typedef unsigned short u16;
typedef u16 u16x8 __attribute__((ext_vector_type(8)));
typedef short s16x8 __attribute__((ext_vector_type(8)));
typedef float f32x4 __attribute__((ext_vector_type(4)));
typedef unsigned int u32;

#define NN 24
#define TT 49
#define MR 784                  // B*T = 16*49
#define SZT 4816896             // B*T*N*H

__device__ inline u16 f2b(float f){
    __hip_bfloat16 b = __float2bfloat16(f); u16 r; __builtin_memcpy(&r, &b, 2); return r;
}
__device__ inline float sig_(float x){ return 1.f / (1.f + __expf(-x)); }
__device__ inline float tanh_(float x){ float e = __expf(2.f * x); return (e - 1.f) / (e + 1.f); }

__device__ inline void gld16(const u16* g, u16* l){
    __builtin_amdgcn_global_load_lds(
        (const __attribute__((address_space(1))) unsigned int*)g,
        (__attribute__((address_space(3))) unsigned int*)l, 16, 0, 0);
}

#define BAR()      __builtin_amdgcn_s_barrier()
#define WAITVM(N)  asm volatile("s_waitcnt vmcnt(" #N ")" ::: "memory")
#define WAITVL(N)  asm volatile("s_waitcnt vmcnt(" #N ") lgkmcnt(0)" ::: "memory")

// ws layout: WT0 bf16 [216][56][256][32] | WT1 bf16 [144][16][256][32] | Abf bf16 [24][56][784][32]
#define WT0_ELEMS ((size_t)216 * 256 * 1792)
#define WT1_ELEMS ((size_t)144 * 256 * 512)

// ===========================================================================
// Merged prepass: wprep0 (24192 blk) | wprep1 (4608 blk) | aprep (17472 blk)
// ===========================================================================
__global__ __launch_bounds__(256) void prep_all(
    const float* __restrict__ U,  const float* __restrict__ Wt,
    const float* __restrict__ Ws, const float* __restrict__ Zt,
    const float* __restrict__ Zs, const float* __restrict__ Wg,
    const float* __restrict__ Zg,
    const float* __restrict__ p,  const float* __restrict__ h,
    const float* __restrict__ g_t, const float* __restrict__ g_s,
    u16* __restrict__ wt0, u16* __restrict__ wt1, u16* __restrict__ Abf)
{
    __shared__ u16 T[64][72];
    const int tid = threadIdx.x;
    const int lin = blockIdx.x;

    if (lin < 24192) {
        const int kt = lin % 28, ct = (lin / 28) % 4, z = lin / 112;
        const int n = z % NN, g = z / NN;
        const int k0 = kt * 64;
        const float* wbase;
        if (k0 < 256)       wbase = U  + (size_t)((g * NN + n) * 256 + k0)          * 256;
        else if (k0 < 1024) wbase = Wt + (size_t)((g * NN + n) * 768 + (k0 - 256))  * 256;
        else if (k0 < 1280) wbase = Ws + (size_t)((g * NN + n) * 256 + (k0 - 1024)) * 256;
        else if (k0 < 1536) wbase = Zt + (size_t)((g * NN + n) * 256 + (k0 - 1280)) * 256;
        else { const int g2 = (g == 2) ? 1 : g;      // Zs_eff: f_ft uses Zs[lt]
               wbase = Zs + (size_t)((g2 * NN + n) * 256 + (k0 - 1536)) * 256; }
        const int colg = ct * 64 + (tid & 15) * 4;
        #pragma unroll
        for (int it = 0; it < 4; ++it) {
            const int krl = (tid >> 4) + it * 16;
            const float4 v = *(const float4*)(wbase + (size_t)krl * 256 + colg);
            const int cl = (tid & 15) * 4;
            T[cl + 0][krl] = f2b(v.x); T[cl + 1][krl] = f2b(v.y);
            T[cl + 2][krl] = f2b(v.z); T[cl + 3][krl] = f2b(v.w);
        }
        __syncthreads();
        const int col_l = tid >> 2, ks = (tid & 3) * 16;
        const int ktile = 2 * kt + (ks >> 5);
        const int koff  = ks & 31;
        u16* dst = wt0 + (size_t)z * 458752 + (size_t)ktile * 8192
                       + (size_t)(ct * 64 + col_l) * 32 + koff;
        u16x8 w0, w1;
        #pragma unroll
        for (int j2 = 0; j2 < 8; ++j2) { w0[j2] = T[col_l][ks + j2]; w1[j2] = T[col_l][ks + 8 + j2]; }
        *(u16x8*)(dst) = w0; *(u16x8*)(dst + 8) = w1;
    } else if (lin < 28800) {
        const int l = lin - 24192;
        const int kt = l % 8, ct = (l / 8) % 4, z = l / 32;
        const int k0 = kt * 64;
        const float* wbase = (k0 < 256)
            ? Wg + (size_t)(z * 256 + k0) * 256
            : Zg + (size_t)(z * 256 + (k0 - 256)) * 256;
        const int colg = ct * 64 + (tid & 15) * 4;
        #pragma unroll
        for (int it = 0; it < 4; ++it) {
            const int krl = (tid >> 4) + it * 16;
            const float4 v = *(const float4*)(wbase + (size_t)krl * 256 + colg);
            const int cl = (tid & 15) * 4;
            T[cl + 0][krl] = f2b(v.x); T[cl + 1][krl] = f2b(v.y);
            T[cl + 2][krl] = f2b(v.z); T[cl + 3][krl] = f2b(v.w);
        }
        __syncthreads();
        const int col_l = tid >> 2, ks = (tid & 3) * 16;
        const int ktile = 2 * kt + (ks >> 5);
        const int koff  = ks & 31;
        u16* dst = wt1 + (size_t)z * 131072 + (size_t)ktile * 8192
                       + (size_t)(ct * 64 + col_l) * 32 + koff;
        u16x8 w0, w1;
        #pragma unroll
        for (int j2 = 0; j2 < 8; ++j2) { w0[j2] = T[col_l][ks + j2]; w1[j2] = T[col_l][ks + 8 + j2]; }
        *(u16x8*)(dst) = w0; *(u16x8*)(dst + 8) = w1;
    } else {
        const int l = lin - 28800;
        const int bx = l % 13, kt = (l / 13) % 56, n = l / 728;
        const int row = bx * 64 + (tid >> 2);
        if (row >= MR) return;
        const int c  = tid & 3;
        const int kg = kt * 32 + c * 8;
        const int seg = kg >> 8, koff = kg & 255;
        const int ec = (row * NN + n) * 256 + koff;
        const float* src = nullptr; bool valid = true;
        switch (seg) {
            case 0: src = p + ec; break;
            case 1: valid = (n > 0);          src = h + ec - 256; break;
            case 2: src = h + ec; break;
            case 3: valid = (n < NN - 1);     src = h + ec + 256; break;
            case 4: valid = (row % TT) != 0;  src = h + ec - NN * 256; break;
            case 5: src = g_t + ec; break;
            default: src = g_s + ec; break;
        }
        float4 lo = {0.f,0.f,0.f,0.f}, hi = lo;
        if (valid) { lo = *(const float4*)src; hi = *(const float4*)(src + 4); }
        u16x8 w;
        w[0] = f2b(lo.x); w[1] = f2b(lo.y); w[2] = f2b(lo.z); w[3] = f2b(lo.w);
        w[4] = f2b(hi.x); w[5] = f2b(hi.y); w[6] = f2b(hi.z); w[7] = f2b(hi.w);
        *(u16x8*)(Abf + ((size_t)(n * 56 + kt) * MR + row) * 32 + c * 8) = w;
    }
}

// ===========================================================================
// Phase 0: 112x64 tile (784 = 7x112, exact), 8 waves (2rh x 4cq),
// 3-buffer single-barrier counted-vmcnt DMA pipeline, prefetch distance 2.
// LDS: 3 x (3584 + 18432) elems = 132096 B. 1 block/CU (2 waves/SIMD).
// ===========================================================================
#define ABUF9 3584
#define BBUF9 18432
#define BUFE9 (ABUF9 + BBUF9)   // 22016 elems per buffer

__global__ __launch_bounds__(512, 1) void fused_cell9(
    const float* __restrict__ c_h, const float* __restrict__ c_g_t,
    const float* __restrict__ c_g_s,
    const u16* __restrict__ Abf, const u16* __restrict__ WT0,
    const float* __restrict__ Bias,
    float* __restrict__ h_new, float* __restrict__ c_h_new)
{
    extern __shared__ u16 smem[];   // [buf0|buf1|buf2]

    const int tid = threadIdx.x;
    const int lin = blockIdx.x;
    const int xcd = lin & 7, jj = lin >> 3;
    const int mtile = jj % 7;                // 112-row tiles, 7 per slab (exact)
    const int slab  = (jj / 7) * 8 + xcd;    // 0..95
    const int ntile = slab & 3, n = slab >> 2;

    const int wave = tid >> 6, lane = tid & 63;
    const int rh = wave >> 2, cq = wave & 3;
    const int lrow = lane & 15, lci = lane >> 4;
    const int MC = (rh == 0) ? 4 : 3;        // m-frags: rh0 rows 0-63, rh1 rows 64-111

    // ---- A granule (waves 0..6): 16 rows x 32 k, pre-swizzled source
    const int rloc = (wave < 7) ? (wave * 16 + (lane >> 2)) : 0;
    const int ach  = (lane & 3) ^ ((rloc >> 1) & 3);
    const u16* aSrc = Abf + ((size_t)(n * 56) * MR + mtile * 112 + rloc) * 32 + ach * 8;
    const int aDst = wave * 512 + lane * 8;

    // ---- B granules: G = g*4+q; wave w takes G = w, w+8, w+16, w+24 (+w+32 if w<4)
    const int ng = (wave < 4) ? 5 : 4;
    const u16* bSrc[5]; int bDst[5];
    #pragma unroll
    for (int i = 0; i < 5; ++i) {
        const int G = (i < ng) ? (wave + 8 * i) : 0;
        const int g = G >> 2, q = G & 3;
        const int c = q * 16 + (lane >> 2);
        const int ch = (lane & 3) ^ ((c >> 1) & 3);
        bSrc[i] = WT0 + (size_t)n * 458752 + (size_t)g * 11010048
                + (size_t)(ntile * 64 + c) * 32 + ch * 8;
        bDst[i] = ABUF9 + g * 2048 + q * 512 + lane * 8;   // FIX: +ABUF9 base
    }

    // ---- fragment read offsets (XOR matches pre-swizzled sources)
    int aro[4];
    #pragma unroll
    for (int m = 0; m < 4; ++m) {
        const int row = rh * 64 + m * 16 + lrow;
        aro[m] = row * 32 + ((lci ^ ((row >> 1) & 3)) << 3);
    }
    const int colr = cq * 16 + lrow;
    const int bro  = ABUF9 + colr * 32 + ((lci ^ ((colr >> 1) & 3)) << 3);

    f32x4 acc[9][4];
    #pragma unroll
    for (int g = 0; g < 9; ++g)
        #pragma unroll
        for (int m = 0; m < 4; ++m) acc[g][m] = f32x4{0.f, 0.f, 0.f, 0.f};

    auto dma = [&](int kt, int buf) {
        u16* base = smem + buf * BUFE9;
        if (wave < 7) gld16(aSrc + (size_t)kt * (MR * 32), base + aDst);
        const size_t ko = (size_t)kt * 8192;
        #pragma unroll
        for (int i = 0; i < 5; ++i)
            if (i < ng) gld16(bSrc[i] + ko, base + bDst[i]);
    };
    auto waitw = [&]() {       // wait for previous tile's granules (counted, per wave)
        if (wave < 4)      { WAITVM(6); }
        else if (wave < 7) { WAITVM(5); }
        else               { WAITVM(4); }
    };
    auto domfma = [&](int buf) {
        const u16* base = smem + buf * BUFE9;
        s16x8 af[4];
        #pragma unroll
        for (int m = 0; m < 4; ++m)
            if (m < MC) af[m] = *(const s16x8*)(&base[aro[m]]);
        __builtin_amdgcn_s_setprio(1);
        #pragma unroll
        for (int g = 0; g < 9; ++g) {
            const s16x8 bf = *(const s16x8*)(&base[g * 2048 + bro]);
            #pragma unroll
            for (int m = 0; m < 4; ++m)
                if (m < MC)
                    acc[g][m] = __builtin_amdgcn_mfma_f32_16x16x32_bf16(af[m], bf, acc[g][m], 0, 0, 0);
        }
        __builtin_amdgcn_s_setprio(0);
    };

    // prologue: tiles 0,1 in flight; publish tile 0
    dma(0, 0); dma(1, 1);
    waitw(); BAR();
    // main: phases 0..53 (buf = T%3); dma(T+2) leads by 2 phases; 1 barrier/phase
    for (int t3 = 0; t3 < 54; t3 += 3) {
        dma(t3 + 2, 2); domfma(0); waitw(); BAR();
        dma(t3 + 3, 0); domfma(1); waitw(); BAR();
        dma(t3 + 4, 1); domfma(2); waitw(); BAR();
    }
    domfma(0);                    // T = 54
    WAITVM(0); BAR();             // tile 55 fully landed
    domfma(1);                    // T = 55

    // ---- epilogue: bias + cell update, f32 stores (no row guard: exact tiling)
    const int col = ntile * 64 + cq * 16 + lrow;
    float bv[9];
    #pragma unroll
    for (int g = 0; g < 9; ++g) bv[g] = Bias[(g * NN + n) * 256 + col];

    #pragma unroll
    for (int m = 0; m < 4; ++m) {
        if (m < MC) {
            #pragma unroll
            for (int i = 0; i < 4; ++i) {
                const int row = mtile * 112 + rh * 64 + m * 16 + (lane >> 4) * 4 + i;
                const size_t e = ((size_t)(row * NN + n)) * 256 + col;
                const float i_n  = sig_(acc[0][m][i] + bv[0]);
                const float f_lt = sig_(acc[1][m][i] + bv[1]);
                const float f_ft = sig_(acc[2][m][i] + bv[2]);
                const float f_rt = sig_(acc[3][m][i] + bv[3]);
                const float f_s  = sig_(acc[4][m][i] + bv[4]);
                const float f_gt = sig_(acc[5][m][i] + bv[5]);
                const float f_gs = sig_(acc[6][m][i] + bv[6]);
                const float o_n  = sig_(acc[7][m][i] + bv[7]);
                const float c_n  = tanh_(acc[8][m][i] + bv[8]);
                const float cb = (n > 0)      ? c_h[e - 256] : 0.f;
                const float ca = (n < NN - 1) ? c_h[e + 256] : 0.f;
                const float cs = (row % TT)   ? c_h[e - NN * 256] : 0.f;
                const float cn = f_lt * cb + f_ft * c_h[e] + f_rt * ca
                               + f_s * cs + f_gt * c_g_t[e] + f_gs * c_g_s[e]
                               + i_n * c_n;
                c_h_new[e] = cn;
                h_new[e]   = o_n * tanh_(cn);
            }
        }
    }
}

// ===========================================================================
// Phase 1: counted-vmcnt pipeline + T14 split A-staging (r10, unchanged).
// ===========================================================================
__global__ __launch_bounds__(256, 4) void fused_global5(
    const float* __restrict__ hn,   const float* __restrict__ g_t,
    const float* __restrict__ g_s,  const float* __restrict__ c_g_t,
    const float* __restrict__ c_g_s,
    const u16* __restrict__ WT1, const float* __restrict__ Bg,
    float* __restrict__ out2, float* __restrict__ out3,
    float* __restrict__ out4, float* __restrict__ out5)
{
    __shared__ u16 smem[2 * 2048 + 2 * 6144];

    const int tid = threadIdx.x;
    const int lin = blockIdx.x;
    const int xcd = lin & 7, j = lin >> 3;
    const int mtile = j % 13;
    const int slab  = (j / 13) * 8 + xcd;   // 0..191
    const int ntile = slab & 3;
    const int zz    = slab >> 2;            // 0..47
    const int n = zz % NN, grp = zz / NN;

    const float* xg = grp ? g_s : g_t;
    const float* cg = grp ? c_g_s : c_g_t;
    float* og  = grp ? out4 : out2;
    float* ocg = grp ? out5 : out3;

    const int s_r = tid >> 2, s_c = tid & 3;
    const int gr  = mtile * 64 + s_r;
    const bool mval = (gr < MR);
    const int ec = (gr * NN + n) * 256;

    const int wro = s_r * 32 + ((s_c ^ ((s_r >> 1) & 3)) << 3);

    const int wave = tid >> 6, lane = tid & 63;
    const int lrow = lane & 15, lci = lane >> 4;

    int aro[4];
    #pragma unroll
    for (int m = 0; m < 4; ++m) {
        const int row = m * 16 + lrow;
        aro[m] = row * 32 + ((lci ^ ((row >> 1) & 3)) << 3);
    }
    const int colr = wave * 16 + lrow;
    const int bro  = colr * 32 + ((lci ^ ((colr >> 1) & 3)) << 3);

    const u16* wbase = WT1 + (size_t)(grp * 3 * NN + n) * 131072
                           + (size_t)(ntile * 64) * 32 + wro;

    f32x4 acc[3][4];
    #pragma unroll
    for (int g = 0; g < 3; ++g)
        #pragma unroll
        for (int m = 0; m < 4; ++m) acc[g][m] = f32x4{0.f, 0.f, 0.f, 0.f};

    float4 aOlo, aOhi, aNlo, aNhi;

    auto loadA = [&](int kt, float4& lo, float4& hi) {
        const int K0 = kt * 32, koff = (K0 & 255) + s_c * 8;
        const float* src = ((K0 < 256) ? hn : xg) + ec + koff;
        lo = make_float4(0.f, 0.f, 0.f, 0.f); hi = lo;
        if (mval) { lo = *(const float4*)src; hi = *(const float4*)(src + 4); }
    };
    auto storeA = [&](int buf, const float4& lo, const float4& hi) {
        u16x8 aw;
        aw[0] = f2b(lo.x); aw[1] = f2b(lo.y); aw[2] = f2b(lo.z); aw[3] = f2b(lo.w);
        aw[4] = f2b(hi.x); aw[5] = f2b(hi.y); aw[6] = f2b(hi.z); aw[7] = f2b(hi.w);
        *(u16x8*)(&smem[buf * 2048 + wro]) = aw;
    };
    auto dmaB = [&](int kt, int buf) {
        const u16* wb = wbase + (size_t)kt * 8192;
        u16* dst = &smem[2 * 2048 + buf * 6144 + tid * 8];
        #pragma unroll
        for (int g = 0; g < 3; ++g)
            gld16(wb + (size_t)g * 3145728, dst + g * 2048);
    };
    auto domfma = [&](int buf) {
        const u16* Asb = smem + buf * 2048;
        const u16* Bsb = smem + 2 * 2048 + buf * 6144;
        s16x8 af[4];
        #pragma unroll
        for (int m = 0; m < 4; ++m) af[m] = *(const s16x8*)(&Asb[aro[m]]);
        __builtin_amdgcn_s_setprio(1);
        #pragma unroll
        for (int g = 0; g < 3; ++g) {
            const s16x8 bf = *(const s16x8*)(&Bsb[g * 2048 + bro]);
            #pragma unroll
            for (int m = 0; m < 4; ++m)
                acc[g][m] = __builtin_amdgcn_mfma_f32_16x16x32_bf16(af[m], bf, acc[g][m], 0, 0, 0);
        }
        __builtin_amdgcn_s_setprio(0);
    };

    loadA(0, aOlo, aOhi);
    dmaB(0, 0);
    storeA(0, aOlo, aOhi);
    loadA(1, aOlo, aOhi);
    dmaB(1, 1);
    WAITVL(5); BAR();
    for (int kt = 0; kt < 14; kt += 2) {
        domfma(0);
        BAR();
        loadA(kt + 2, aNlo, aNhi);
        dmaB(kt + 2, 0);
        storeA(1, aOlo, aOhi);
        WAITVL(5); BAR();
        domfma(1);
        BAR();
        loadA(kt + 3, aOlo, aOhi);
        dmaB(kt + 3, 1);
        storeA(0, aNlo, aNhi);
        WAITVL(5); BAR();
    }
    domfma(0);
    BAR();
    storeA(1, aOlo, aOhi);
    WAITVL(0); BAR();
    domfma(1);

    const int col = ntile * 64 + wave * 16 + lrow;
    float bv[3];
    #pragma unroll
    for (int g = 0; g < 3; ++g) bv[g] = Bg[((grp * 3 + g) * NN + n) * 256 + col];

    #pragma unroll
    for (int m = 0; m < 4; ++m) {
        #pragma unroll
        for (int i = 0; i < 4; ++i) {
            const int row = mtile * 64 + m * 16 + (lane >> 4) * 4 + i;
            if (row < MR) {
                const size_t e = ((size_t)(row * NN + n)) * 256 + col;
                const float f    = sig_(acc[0][m][i] + bv[0]);
                const float cand = tanh_(acc[1][m][i] + bv[1]);
                const float o    = sig_(acc[2][m][i] + bv[2]);
                const float cn = f * cg[e] + (1.f - f) * cand;
                ocg[e] = cn;
                og[e]  = o * tanh_(cn);
            }
        }
    }
}

extern "C" void kernel_launch(void* const* d_in, const int* in_sizes, int n_in,
                              void* d_out, int out_size, void* d_ws, size_t ws_size,
                              hipStream_t stream)
{
    const float* h     = (const float*)d_in[0];
    const float* c_h   = (const float*)d_in[1];
    const float* p     = (const float*)d_in[2];
    const float* g_t   = (const float*)d_in[3];
    const float* c_g_t = (const float*)d_in[4];
    const float* g_s   = (const float*)d_in[5];
    const float* c_g_s = (const float*)d_in[6];
    const float* U     = (const float*)d_in[7];
    const float* Wt    = (const float*)d_in[8];
    const float* Ws    = (const float*)d_in[9];
    const float* Zt    = (const float*)d_in[10];
    const float* Zs    = (const float*)d_in[11];
    const float* bb    = (const float*)d_in[12];
    const float* Wg    = (const float*)d_in[13];
    const float* Zg    = (const float*)d_in[14];
    const float* bg    = (const float*)d_in[15];

    float* out0 = (float*)d_out;        // h_new
    float* out1 = out0 + (size_t)SZT;   // c_h_new
    float* out2 = out1 + (size_t)SZT;   // g_t_new
    float* out3 = out2 + (size_t)SZT;   // c_g_t_new
    float* out4 = out3 + (size_t)SZT;   // g_s_new
    float* out5 = out4 + (size_t)SZT;   // c_g_s_new

    u16* wt0 = (u16*)d_ws;
    u16* wt1 = wt0 + WT0_ELEMS;
    u16* abf = wt1 + WT1_ELEMS;

    dim3 blk(256);
    prep_all<<<dim3(46272), blk, 0, stream>>>(U, Wt, Ws, Zt, Zs, Wg, Zg,
                                              p, h, g_t, g_s, wt0, wt1, abf);

    const int ldsBytes = 3 * BUFE9 * (int)sizeof(u16);   // 132096
    hipFuncSetAttribute((const void*)fused_cell9,
                        hipFuncAttributeMaxDynamicSharedMemorySize, ldsBytes);
    fused_cell9<<<dim3(672), dim3(512), ldsBytes, stream>>>(
        c_h, c_g_t, c_g_s, abf, wt0, bb, out0, out1);
    fused_global5<<<dim3(2496), blk, 0, stream>>>(
        out0, g_t, g_s, c_g_t, c_g_s, wt1, bg, out2, out3, out4, out5);
}

// Round 15
// 448.641 us; speedup vs baseline: 1.1430x; 1.0087x over previous
//
#include <hip/hip_runtime.h>
#include <hip/hip_bf16.h>

typedef unsigned short u16;
typedef u16 u16x8 __attribute__((ext_vector_type(8)));
typedef short s16x8 __attribute__((ext_vector_type(8)));
typedef float f32x4 __attribute__((ext_vector_type(4)));
typedef unsigned int u32;

#define NN 24
#define TT 49
#define MR 784                  // B*T = 16*49
#define SZT 4816896             // B*T*N*H

__device__ inline u16 f2b(float f){
    __hip_bfloat16 b = __float2bfloat16(f); u16 r; __builtin_memcpy(&r, &b, 2); return r;
}
__device__ inline float sig_(float x){ return 1.f / (1.f + __expf(-x)); }
__device__ inline float tanh_(float x){ float e = __expf(2.f * x); return (e - 1.f) / (e + 1.f); }

__device__ inline void gld16(const u16* g, u16* l){
    __builtin_amdgcn_global_load_lds(
        (const __attribute__((address_space(1))) unsigned int*)g,
        (__attribute__((address_space(3))) unsigned int*)l, 16, 0, 0);
}

#define BAR()      __builtin_amdgcn_s_barrier()
#define WAITVM(N)  asm volatile("s_waitcnt vmcnt(" #N ")" ::: "memory")
#define WAITVL(N)  asm volatile("s_waitcnt vmcnt(" #N ") lgkmcnt(0)" ::: "memory")

// ws layout: WT0 bf16 [216][56][256][32] | WT1 bf16 [144][16][256][32] | Abf bf16 [24][56][784][32]
#define WT0_ELEMS ((size_t)216 * 256 * 1792)
#define WT1_ELEMS ((size_t)144 * 256 * 512)

// ===========================================================================
// Merged prepass: wprep0 (24192 blk) | wprep1 (4608 blk) | aprep (17472 blk)
// ===========================================================================
__global__ __launch_bounds__(256) void prep_all(
    const float* __restrict__ U,  const float* __restrict__ Wt,
    const float* __restrict__ Ws, const float* __restrict__ Zt,
    const float* __restrict__ Zs, const float* __restrict__ Wg,
    const float* __restrict__ Zg,
    const float* __restrict__ p,  const float* __restrict__ h,
    const float* __restrict__ g_t, const float* __restrict__ g_s,
    u16* __restrict__ wt0, u16* __restrict__ wt1, u16* __restrict__ Abf)
{
    __shared__ u16 T[64][72];
    const int tid = threadIdx.x;
    const int lin = blockIdx.x;

    if (lin < 24192) {
        const int kt = lin % 28, ct = (lin / 28) % 4, z = lin / 112;
        const int n = z % NN, g = z / NN;
        const int k0 = kt * 64;
        const float* wbase;
        if (k0 < 256)       wbase = U  + (size_t)((g * NN + n) * 256 + k0)          * 256;
        else if (k0 < 1024) wbase = Wt + (size_t)((g * NN + n) * 768 + (k0 - 256))  * 256;
        else if (k0 < 1280) wbase = Ws + (size_t)((g * NN + n) * 256 + (k0 - 1024)) * 256;
        else if (k0 < 1536) wbase = Zt + (size_t)((g * NN + n) * 256 + (k0 - 1280)) * 256;
        else { const int g2 = (g == 2) ? 1 : g;      // Zs_eff: f_ft uses Zs[lt]
               wbase = Zs + (size_t)((g2 * NN + n) * 256 + (k0 - 1536)) * 256; }
        const int colg = ct * 64 + (tid & 15) * 4;
        #pragma unroll
        for (int it = 0; it < 4; ++it) {
            const int krl = (tid >> 4) + it * 16;
            const float4 v = *(const float4*)(wbase + (size_t)krl * 256 + colg);
            const int cl = (tid & 15) * 4;
            T[cl + 0][krl] = f2b(v.x); T[cl + 1][krl] = f2b(v.y);
            T[cl + 2][krl] = f2b(v.z); T[cl + 3][krl] = f2b(v.w);
        }
        __syncthreads();
        const int col_l = tid >> 2, ks = (tid & 3) * 16;
        const int ktile = 2 * kt + (ks >> 5);
        const int koff  = ks & 31;
        u16* dst = wt0 + (size_t)z * 458752 + (size_t)ktile * 8192
                       + (size_t)(ct * 64 + col_l) * 32 + koff;
        u16x8 w0, w1;
        #pragma unroll
        for (int j2 = 0; j2 < 8; ++j2) { w0[j2] = T[col_l][ks + j2]; w1[j2] = T[col_l][ks + 8 + j2]; }
        *(u16x8*)(dst) = w0; *(u16x8*)(dst + 8) = w1;
    } else if (lin < 28800) {
        const int l = lin - 24192;
        const int kt = l % 8, ct = (l / 8) % 4, z = l / 32;
        const int k0 = kt * 64;
        const float* wbase = (k0 < 256)
            ? Wg + (size_t)(z * 256 + k0) * 256
            : Zg + (size_t)(z * 256 + (k0 - 256)) * 256;
        const int colg = ct * 64 + (tid & 15) * 4;
        #pragma unroll
        for (int it = 0; it < 4; ++it) {
            const int krl = (tid >> 4) + it * 16;
            const float4 v = *(const float4*)(wbase + (size_t)krl * 256 + colg);
            const int cl = (tid & 15) * 4;
            T[cl + 0][krl] = f2b(v.x); T[cl + 1][krl] = f2b(v.y);
            T[cl + 2][krl] = f2b(v.z); T[cl + 3][krl] = f2b(v.w);
        }
        __syncthreads();
        const int col_l = tid >> 2, ks = (tid & 3) * 16;
        const int ktile = 2 * kt + (ks >> 5);
        const int koff  = ks & 31;
        u16* dst = wt1 + (size_t)z * 131072 + (size_t)ktile * 8192
                       + (size_t)(ct * 64 + col_l) * 32 + koff;
        u16x8 w0, w1;
        #pragma unroll
        for (int j2 = 0; j2 < 8; ++j2) { w0[j2] = T[col_l][ks + j2]; w1[j2] = T[col_l][ks + 8 + j2]; }
        *(u16x8*)(dst) = w0; *(u16x8*)(dst + 8) = w1;
    } else {
        const int l = lin - 28800;
        const int bx = l % 13, kt = (l / 13) % 56, n = l / 728;
        const int row = bx * 64 + (tid >> 2);
        if (row >= MR) return;
        const int c  = tid & 3;
        const int kg = kt * 32 + c * 8;
        const int seg = kg >> 8, koff = kg & 255;
        const int ec = (row * NN + n) * 256 + koff;
        const float* src = nullptr; bool valid = true;
        switch (seg) {
            case 0: src = p + ec; break;
            case 1: valid = (n > 0);          src = h + ec - 256; break;
            case 2: src = h + ec; break;
            case 3: valid = (n < NN - 1);     src = h + ec + 256; break;
            case 4: valid = (row % TT) != 0;  src = h + ec - NN * 256; break;
            case 5: src = g_t + ec; break;
            default: src = g_s + ec; break;
        }
        float4 lo = {0.f,0.f,0.f,0.f}, hi = lo;
        if (valid) { lo = *(const float4*)src; hi = *(const float4*)(src + 4); }
        u16x8 w;
        w[0] = f2b(lo.x); w[1] = f2b(lo.y); w[2] = f2b(lo.z); w[3] = f2b(lo.w);
        w[4] = f2b(hi.x); w[5] = f2b(hi.y); w[6] = f2b(hi.z); w[7] = f2b(hi.w);
        *(u16x8*)(Abf + ((size_t)(n * 56 + kt) * MR + row) * 32 + c * 8) = w;
    }
}

// ===========================================================================
// Phase 0: 112x32 tile, 4 waves (rh2 x cq2), 9 gates. 3-buffer single-barrier
// counted-vmcnt pipeline (distance 2). 2 blocks/CU (independent barrier
// groups decouple DMA-return jitter). LDS 3 x 25600 B = 76800 B.
// Per wave per dma: A granules {w, w+4} (w<3: 2, w3: 1) + B granules with
// q = w&1, gates (w>>1)+2i (w<2: 5, else 4). waitw = 7/7/6/5.
// ===========================================================================
#define AB10 3584               // A: 112 rows x 32 k
#define BB10 9216               // B: 9 gates x 32 cols x 32 k
#define BUFE10 (AB10 + BB10)    // 12800 elems per buffer

__global__ __launch_bounds__(256, 2) void fused_cell10(
    const float* __restrict__ c_h, const float* __restrict__ c_g_t,
    const float* __restrict__ c_g_s,
    const u16* __restrict__ Abf, const u16* __restrict__ WT0,
    const float* __restrict__ Bias,
    float* __restrict__ h_new, float* __restrict__ c_h_new)
{
    extern __shared__ u16 smem[];   // [buf0|buf1|buf2]

    const int tid = threadIdx.x;
    const int lin = blockIdx.x;
    const int xcd = lin & 7, jj = lin >> 3;
    const int mtile = jj % 7;                // 112-row tiles (exact)
    const int slab  = (jj / 7) * 8 + xcd;    // 0..191
    const int ntile = slab & 7, n = slab >> 3;   // 8 ntiles of 32 cols

    const int wave = tid >> 6, lane = tid & 63;
    const int rh = wave >> 1, cq = wave & 1;
    const int lrow = lane & 15, lci = lane >> 4;
    const int MC = (rh == 0) ? 4 : 3;

    // ---- A granules (pre-swizzled source, linear dest)
    const int nga = (wave < 3) ? 2 : 1;
    const u16* aSrc[2]; int aDst[2];
    #pragma unroll
    for (int i = 0; i < 2; ++i) {
        const int a = (i < nga) ? (wave + 4 * i) : 0;
        const int r = a * 16 + (lane >> 2);
        const int ach = (lane & 3) ^ ((r >> 1) & 3);
        aSrc[i] = Abf + ((size_t)(n * 56) * MR + mtile * 112 + r) * 32 + ach * 8;
        aDst[i] = a * 512 + lane * 8;
    }

    // ---- B granules: q = wave&1 fixed; gates g = (wave>>1) + 2i
    const int ngb = (wave < 2) ? 5 : 4;
    const int qb  = wave & 1;
    const int cb  = qb * 16 + (lane >> 2);           // local col 0..31
    const int chb = (lane & 3) ^ ((cb >> 1) & 3);
    const u16* bBase = WT0 + (size_t)n * 458752
                     + (size_t)(ntile * 32 + cb) * 32 + chb * 8;
    const int bDst0 = AB10 + qb * 512 + lane * 8;
    const int gb0 = wave >> 1;                        // first gate; step 2

    // ---- fragment read offsets
    int aro[4];
    #pragma unroll
    for (int m = 0; m < 4; ++m) {
        const int row = rh * 64 + m * 16 + lrow;
        aro[m] = row * 32 + ((lci ^ ((row >> 1) & 3)) << 3);
    }
    const int colr = cq * 16 + lrow;                  // local col 0..31
    const int bro  = AB10 + colr * 32 + ((lci ^ ((colr >> 1) & 3)) << 3);

    f32x4 acc[9][4];
    #pragma unroll
    for (int g = 0; g < 9; ++g)
        #pragma unroll
        for (int m = 0; m < 4; ++m) acc[g][m] = f32x4{0.f, 0.f, 0.f, 0.f};

    auto dma = [&](int kt, int buf) {
        u16* base = smem + buf * BUFE10;
        const size_t koA = (size_t)kt * (MR * 32);
        #pragma unroll
        for (int i = 0; i < 2; ++i)
            if (i < nga) gld16(aSrc[i] + koA, base + aDst[i]);
        const size_t koB = (size_t)kt * 8192;
        #pragma unroll
        for (int i = 0; i < 5; ++i)
            if (i < ngb) gld16(bBase + koB + (size_t)(gb0 + 2 * i) * 11010048,
                               base + bDst0 + (gb0 + 2 * i) * 1024);
    };
    auto waitw = [&]() {
        if (wave < 2)       { WAITVM(7); }
        else if (wave == 2) { WAITVM(6); }
        else                { WAITVM(5); }
    };
    auto domfma = [&](int buf) {
        const u16* base = smem + buf * BUFE10;
        s16x8 af[4];
        #pragma unroll
        for (int m = 0; m < 4; ++m)
            if (m < MC) af[m] = *(const s16x8*)(&base[aro[m]]);
        __builtin_amdgcn_s_setprio(1);
        #pragma unroll
        for (int g = 0; g < 9; ++g) {
            const s16x8 bf = *(const s16x8*)(&base[g * 1024 + bro]);
            #pragma unroll
            for (int m = 0; m < 4; ++m)
                if (m < MC)
                    acc[g][m] = __builtin_amdgcn_mfma_f32_16x16x32_bf16(af[m], bf, acc[g][m], 0, 0, 0);
        }
        __builtin_amdgcn_s_setprio(0);
    };

    // prologue: tiles 0,1 in flight; publish tile 0
    dma(0, 0); dma(1, 1);
    waitw(); BAR();
    for (int t3 = 0; t3 < 54; t3 += 3) {
        dma(t3 + 2, 2); domfma(0); waitw(); BAR();
        dma(t3 + 3, 0); domfma(1); waitw(); BAR();
        dma(t3 + 4, 1); domfma(2); waitw(); BAR();
    }
    domfma(0);                    // T = 54
    WAITVM(0); BAR();             // tile 55 fully landed
    domfma(1);                    // T = 55

    // ---- epilogue: bias + cell update, f32 stores (exact tiling, no guard)
    const int col = ntile * 32 + cq * 16 + lrow;
    float bv[9];
    #pragma unroll
    for (int g = 0; g < 9; ++g) bv[g] = Bias[(g * NN + n) * 256 + col];

    #pragma unroll
    for (int m = 0; m < 4; ++m) {
        if (m < MC) {
            #pragma unroll
            for (int i = 0; i < 4; ++i) {
                const int row = mtile * 112 + rh * 64 + m * 16 + (lane >> 4) * 4 + i;
                const size_t e = ((size_t)(row * NN + n)) * 256 + col;
                const float i_n  = sig_(acc[0][m][i] + bv[0]);
                const float f_lt = sig_(acc[1][m][i] + bv[1]);
                const float f_ft = sig_(acc[2][m][i] + bv[2]);
                const float f_rt = sig_(acc[3][m][i] + bv[3]);
                const float f_s  = sig_(acc[4][m][i] + bv[4]);
                const float f_gt = sig_(acc[5][m][i] + bv[5]);
                const float f_gs = sig_(acc[6][m][i] + bv[6]);
                const float o_n  = sig_(acc[7][m][i] + bv[7]);
                const float c_n  = tanh_(acc[8][m][i] + bv[8]);
                const float cb_ = (n > 0)      ? c_h[e - 256] : 0.f;
                const float ca_ = (n < NN - 1) ? c_h[e + 256] : 0.f;
                const float cs_ = (row % TT)   ? c_h[e - NN * 256] : 0.f;
                const float cn = f_lt * cb_ + f_ft * c_h[e] + f_rt * ca_
                               + f_s * cs_ + f_gt * c_g_t[e] + f_gs * c_g_s[e]
                               + i_n * c_n;
                c_h_new[e] = cn;
                h_new[e]   = o_n * tanh_(cn);
            }
        }
    }
}

// ===========================================================================
// Phase 1: counted-vmcnt pipeline + T14 split A-staging (r10, unchanged).
// ===========================================================================
__global__ __launch_bounds__(256, 4) void fused_global5(
    const float* __restrict__ hn,   const float* __restrict__ g_t,
    const float* __restrict__ g_s,  const float* __restrict__ c_g_t,
    const float* __restrict__ c_g_s,
    const u16* __restrict__ WT1, const float* __restrict__ Bg,
    float* __restrict__ out2, float* __restrict__ out3,
    float* __restrict__ out4, float* __restrict__ out5)
{
    __shared__ u16 smem[2 * 2048 + 2 * 6144];

    const int tid = threadIdx.x;
    const int lin = blockIdx.x;
    const int xcd = lin & 7, j = lin >> 3;
    const int mtile = j % 13;
    const int slab  = (j / 13) * 8 + xcd;   // 0..191
    const int ntile = slab & 3;
    const int zz    = slab >> 2;            // 0..47
    const int n = zz % NN, grp = zz / NN;

    const float* xg = grp ? g_s : g_t;
    const float* cg = grp ? c_g_s : c_g_t;
    float* og  = grp ? out4 : out2;
    float* ocg = grp ? out5 : out3;

    const int s_r = tid >> 2, s_c = tid & 3;
    const int gr  = mtile * 64 + s_r;
    const bool mval = (gr < MR);
    const int ec = (gr * NN + n) * 256;

    const int wro = s_r * 32 + ((s_c ^ ((s_r >> 1) & 3)) << 3);

    const int wave = tid >> 6, lane = tid & 63;
    const int lrow = lane & 15, lci = lane >> 4;

    int aro[4];
    #pragma unroll
    for (int m = 0; m < 4; ++m) {
        const int row = m * 16 + lrow;
        aro[m] = row * 32 + ((lci ^ ((row >> 1) & 3)) << 3);
    }
    const int colr = wave * 16 + lrow;
    const int bro  = colr * 32 + ((lci ^ ((colr >> 1) & 3)) << 3);

    const u16* wbase = WT1 + (size_t)(grp * 3 * NN + n) * 131072
                           + (size_t)(ntile * 64) * 32 + wro;

    f32x4 acc[3][4];
    #pragma unroll
    for (int g = 0; g < 3; ++g)
        #pragma unroll
        for (int m = 0; m < 4; ++m) acc[g][m] = f32x4{0.f, 0.f, 0.f, 0.f};

    float4 aOlo, aOhi, aNlo, aNhi;

    auto loadA = [&](int kt, float4& lo, float4& hi) {
        const int K0 = kt * 32, koff = (K0 & 255) + s_c * 8;
        const float* src = ((K0 < 256) ? hn : xg) + ec + koff;
        lo = make_float4(0.f, 0.f, 0.f, 0.f); hi = lo;
        if (mval) { lo = *(const float4*)src; hi = *(const float4*)(src + 4); }
    };
    auto storeA = [&](int buf, const float4& lo, const float4& hi) {
        u16x8 aw;
        aw[0] = f2b(lo.x); aw[1] = f2b(lo.y); aw[2] = f2b(lo.z); aw[3] = f2b(lo.w);
        aw[4] = f2b(hi.x); aw[5] = f2b(hi.y); aw[6] = f2b(hi.z); aw[7] = f2b(hi.w);
        *(u16x8*)(&smem[buf * 2048 + wro]) = aw;
    };
    auto dmaB = [&](int kt, int buf) {
        const u16* wb = wbase + (size_t)kt * 8192;
        u16* dst = &smem[2 * 2048 + buf * 6144 + tid * 8];
        #pragma unroll
        for (int g = 0; g < 3; ++g)
            gld16(wb + (size_t)g * 3145728, dst + g * 2048);
    };
    auto domfma = [&](int buf) {
        const u16* Asb = smem + buf * 2048;
        const u16* Bsb = smem + 2 * 2048 + buf * 6144;
        s16x8 af[4];
        #pragma unroll
        for (int m = 0; m < 4; ++m) af[m] = *(const s16x8*)(&Asb[aro[m]]);
        __builtin_amdgcn_s_setprio(1);
        #pragma unroll
        for (int g = 0; g < 3; ++g) {
            const s16x8 bf = *(const s16x8*)(&Bsb[g * 2048 + bro]);
            #pragma unroll
            for (int m = 0; m < 4; ++m)
                acc[g][m] = __builtin_amdgcn_mfma_f32_16x16x32_bf16(af[m], bf, acc[g][m], 0, 0, 0);
        }
        __builtin_amdgcn_s_setprio(0);
    };

    loadA(0, aOlo, aOhi);
    dmaB(0, 0);
    storeA(0, aOlo, aOhi);
    loadA(1, aOlo, aOhi);
    dmaB(1, 1);
    WAITVL(5); BAR();
    for (int kt = 0; kt < 14; kt += 2) {
        domfma(0);
        BAR();
        loadA(kt + 2, aNlo, aNhi);
        dmaB(kt + 2, 0);
        storeA(1, aOlo, aOhi);
        WAITVL(5); BAR();
        domfma(1);
        BAR();
        loadA(kt + 3, aOlo, aOhi);
        dmaB(kt + 3, 1);
        storeA(0, aNlo, aNhi);
        WAITVL(5); BAR();
    }
    domfma(0);
    BAR();
    storeA(1, aOlo, aOhi);
    WAITVL(0); BAR();
    domfma(1);

    const int col = ntile * 64 + wave * 16 + lrow;
    float bv[3];
    #pragma unroll
    for (int g = 0; g < 3; ++g) bv[g] = Bg[((grp * 3 + g) * NN + n) * 256 + col];

    #pragma unroll
    for (int m = 0; m < 4; ++m) {
        #pragma unroll
        for (int i = 0; i < 4; ++i) {
            const int row = mtile * 64 + m * 16 + (lane >> 4) * 4 + i;
            if (row < MR) {
                const size_t e = ((size_t)(row * NN + n)) * 256 + col;
                const float f    = sig_(acc[0][m][i] + bv[0]);
                const float cand = tanh_(acc[1][m][i] + bv[1]);
                const float o    = sig_(acc[2][m][i] + bv[2]);
                const float cn = f * cg[e] + (1.f - f) * cand;
                ocg[e] = cn;
                og[e]  = o * tanh_(cn);
            }
        }
    }
}

extern "C" void kernel_launch(void* const* d_in, const int* in_sizes, int n_in,
                              void* d_out, int out_size, void* d_ws, size_t ws_size,
                              hipStream_t stream)
{
    const float* h     = (const float*)d_in[0];
    const float* c_h   = (const float*)d_in[1];
    const float* p     = (const float*)d_in[2];
    const float* g_t   = (const float*)d_in[3];
    const float* c_g_t = (const float*)d_in[4];
    const float* g_s   = (const float*)d_in[5];
    const float* c_g_s = (const float*)d_in[6];
    const float* U     = (const float*)d_in[7];
    const float* Wt    = (const float*)d_in[8];
    const float* Ws    = (const float*)d_in[9];
    const float* Zt    = (const float*)d_in[10];
    const float* Zs    = (const float*)d_in[11];
    const float* bb    = (const float*)d_in[12];
    const float* Wg    = (const float*)d_in[13];
    const float* Zg    = (const float*)d_in[14];
    const float* bg    = (const float*)d_in[15];

    float* out0 = (float*)d_out;        // h_new
    float* out1 = out0 + (size_t)SZT;   // c_h_new
    float* out2 = out1 + (size_t)SZT;   // g_t_new
    float* out3 = out2 + (size_t)SZT;   // c_g_t_new
    float* out4 = out3 + (size_t)SZT;   // g_s_new
    float* out5 = out4 + (size_t)SZT;   // c_g_s_new

    u16* wt0 = (u16*)d_ws;
    u16* wt1 = wt0 + WT0_ELEMS;
    u16* abf = wt1 + WT1_ELEMS;

    dim3 blk(256);
    prep_all<<<dim3(46272), blk, 0, stream>>>(U, Wt, Ws, Zt, Zs, Wg, Zg,
                                              p, h, g_t, g_s, wt0, wt1, abf);

    const int ldsBytes = 3 * BUFE10 * (int)sizeof(u16);   // 76800
    hipFuncSetAttribute((const void*)fused_cell10,
                        hipFuncAttributeMaxDynamicSharedMemorySize, ldsBytes);
    fused_cell10<<<dim3(1344), blk, ldsBytes, stream>>>(
        c_h, c_g_t, c_g_s, abf, wt0, bb, out0, out1);
    fused_global5<<<dim3(2496), blk, 0, stream>>>(
        out0, g_t, g_s, c_g_t, c_g_s, wt1, bg, out2, out3, out4, out5);
}

// Round 16
// 436.596 us; speedup vs baseline: 1.1745x; 1.0276x over previous
//
#include <hip/hip_runtime.h>
#include <hip/hip_bf16.h>

typedef unsigned short u16;
typedef u16 u16x8 __attribute__((ext_vector_type(8)));
typedef short s16x8 __attribute__((ext_vector_type(8)));
typedef float f32x4 __attribute__((ext_vector_type(4)));
typedef unsigned int u32;

#define NN 24
#define TT 49
#define MR 784                  // B*T = 16*49
#define SZT 4816896             // B*T*N*H

__device__ inline u16 f2b(float f){
    __hip_bfloat16 b = __float2bfloat16(f); u16 r; __builtin_memcpy(&r, &b, 2); return r;
}
__device__ inline float sig_(float x){ return 1.f / (1.f + __expf(-x)); }
__device__ inline float tanh_(float x){ float e = __expf(2.f * x); return (e - 1.f) / (e + 1.f); }

__device__ inline void gld16(const u16* g, u16* l){
    __builtin_amdgcn_global_load_lds(
        (const __attribute__((address_space(1))) unsigned int*)g,
        (__attribute__((address_space(3))) unsigned int*)l, 16, 0, 0);
}

#define BAR()      __builtin_amdgcn_s_barrier()
#define WAITVM(N)  asm volatile("s_waitcnt vmcnt(" #N ")" ::: "memory")
#define WAITVL(N)  asm volatile("s_waitcnt vmcnt(" #N ") lgkmcnt(0)" ::: "memory")

// ws layout: WT0 bf16 [216][56][256][32] | WT1 bf16 [144][16][256][32] | Abf bf16 [24][56][784][32]
#define WT0_ELEMS ((size_t)216 * 256 * 1792)
#define WT1_ELEMS ((size_t)144 * 256 * 512)

// ===========================================================================
// Merged prepass: wprep0 (24192 blk) | wprep1 (4608 blk) | aprep (17472 blk)
// ===========================================================================
__global__ __launch_bounds__(256) void prep_all(
    const float* __restrict__ U,  const float* __restrict__ Wt,
    const float* __restrict__ Ws, const float* __restrict__ Zt,
    const float* __restrict__ Zs, const float* __restrict__ Wg,
    const float* __restrict__ Zg,
    const float* __restrict__ p,  const float* __restrict__ h,
    const float* __restrict__ g_t, const float* __restrict__ g_s,
    u16* __restrict__ wt0, u16* __restrict__ wt1, u16* __restrict__ Abf)
{
    __shared__ u16 T[64][72];
    const int tid = threadIdx.x;
    const int lin = blockIdx.x;

    if (lin < 24192) {
        const int kt = lin % 28, ct = (lin / 28) % 4, z = lin / 112;
        const int n = z % NN, g = z / NN;
        const int k0 = kt * 64;
        const float* wbase;
        if (k0 < 256)       wbase = U  + (size_t)((g * NN + n) * 256 + k0)          * 256;
        else if (k0 < 1024) wbase = Wt + (size_t)((g * NN + n) * 768 + (k0 - 256))  * 256;
        else if (k0 < 1280) wbase = Ws + (size_t)((g * NN + n) * 256 + (k0 - 1024)) * 256;
        else if (k0 < 1536) wbase = Zt + (size_t)((g * NN + n) * 256 + (k0 - 1280)) * 256;
        else { const int g2 = (g == 2) ? 1 : g;      // Zs_eff: f_ft uses Zs[lt]
               wbase = Zs + (size_t)((g2 * NN + n) * 256 + (k0 - 1536)) * 256; }
        const int colg = ct * 64 + (tid & 15) * 4;
        #pragma unroll
        for (int it = 0; it < 4; ++it) {
            const int krl = (tid >> 4) + it * 16;
            const float4 v = *(const float4*)(wbase + (size_t)krl * 256 + colg);
            const int cl = (tid & 15) * 4;
            T[cl + 0][krl] = f2b(v.x); T[cl + 1][krl] = f2b(v.y);
            T[cl + 2][krl] = f2b(v.z); T[cl + 3][krl] = f2b(v.w);
        }
        __syncthreads();
        const int col_l = tid >> 2, ks = (tid & 3) * 16;
        const int ktile = 2 * kt + (ks >> 5);
        const int koff  = ks & 31;
        u16* dst = wt0 + (size_t)z * 458752 + (size_t)ktile * 8192
                       + (size_t)(ct * 64 + col_l) * 32 + koff;
        u16x8 w0, w1;
        #pragma unroll
        for (int j2 = 0; j2 < 8; ++j2) { w0[j2] = T[col_l][ks + j2]; w1[j2] = T[col_l][ks + 8 + j2]; }
        *(u16x8*)(dst) = w0; *(u16x8*)(dst + 8) = w1;
    } else if (lin < 28800) {
        const int l = lin - 24192;
        const int kt = l % 8, ct = (l / 8) % 4, z = l / 32;
        const int k0 = kt * 64;
        const float* wbase = (k0 < 256)
            ? Wg + (size_t)(z * 256 + k0) * 256
            : Zg + (size_t)(z * 256 + (k0 - 256)) * 256;
        const int colg = ct * 64 + (tid & 15) * 4;
        #pragma unroll
        for (int it = 0; it < 4; ++it) {
            const int krl = (tid >> 4) + it * 16;
            const float4 v = *(const float4*)(wbase + (size_t)krl * 256 + colg);
            const int cl = (tid & 15) * 4;
            T[cl + 0][krl] = f2b(v.x); T[cl + 1][krl] = f2b(v.y);
            T[cl + 2][krl] = f2b(v.z); T[cl + 3][krl] = f2b(v.w);
        }
        __syncthreads();
        const int col_l = tid >> 2, ks = (tid & 3) * 16;
        const int ktile = 2 * kt + (ks >> 5);
        const int koff  = ks & 31;
        u16* dst = wt1 + (size_t)z * 131072 + (size_t)ktile * 8192
                       + (size_t)(ct * 64 + col_l) * 32 + koff;
        u16x8 w0, w1;
        #pragma unroll
        for (int j2 = 0; j2 < 8; ++j2) { w0[j2] = T[col_l][ks + j2]; w1[j2] = T[col_l][ks + 8 + j2]; }
        *(u16x8*)(dst) = w0; *(u16x8*)(dst + 8) = w1;
    } else {
        const int l = lin - 28800;
        const int bx = l % 13, kt = (l / 13) % 56, n = l / 728;
        const int row = bx * 64 + (tid >> 2);
        if (row >= MR) return;
        const int c  = tid & 3;
        const int kg = kt * 32 + c * 8;
        const int seg = kg >> 8, koff = kg & 255;
        const int ec = (row * NN + n) * 256 + koff;
        const float* src = nullptr; bool valid = true;
        switch (seg) {
            case 0: src = p + ec; break;
            case 1: valid = (n > 0);          src = h + ec - 256; break;
            case 2: src = h + ec; break;
            case 3: valid = (n < NN - 1);     src = h + ec + 256; break;
            case 4: valid = (row % TT) != 0;  src = h + ec - NN * 256; break;
            case 5: src = g_t + ec; break;
            default: src = g_s + ec; break;
        }
        float4 lo = {0.f,0.f,0.f,0.f}, hi = lo;
        if (valid) { lo = *(const float4*)src; hi = *(const float4*)(src + 4); }
        u16x8 w;
        w[0] = f2b(lo.x); w[1] = f2b(lo.y); w[2] = f2b(lo.z); w[3] = f2b(lo.w);
        w[4] = f2b(hi.x); w[5] = f2b(hi.y); w[6] = f2b(hi.z); w[7] = f2b(hi.w);
        *(u16x8*)(Abf + ((size_t)(n * 56 + kt) * MR + row) * 32 + c * 8) = w;
    }
}

// ===========================================================================
// Phase 0: 112x32 tile, 4 waves, 9 gates, 3-buffer counted-vmcnt pipeline,
// 2 blocks/CU. n-major XCD ownership: XCD k owns n in {k, k+8, k+16} -> A(n)
// slab (2.8 MB) is L2-resident on its XCD; B(n,ntile) hot across 7 mtiles.
// ===========================================================================
#define AB10 3584               // A: 112 rows x 32 k
#define BB10 9216               // B: 9 gates x 32 cols x 32 k
#define BUFE10 (AB10 + BB10)    // 12800 elems per buffer

__global__ __launch_bounds__(256, 2) void fused_cell10(
    const float* __restrict__ c_h, const float* __restrict__ c_g_t,
    const float* __restrict__ c_g_s,
    const u16* __restrict__ Abf, const u16* __restrict__ WT0,
    const float* __restrict__ Bias,
    float* __restrict__ h_new, float* __restrict__ c_h_new)
{
    extern __shared__ u16 smem[];   // [buf0|buf1|buf2]

    const int tid = threadIdx.x;
    const int lin = blockIdx.x;
    // n-major XCD decode: xcd owns n = nIdx*8+xcd; within: ntile-mid, mtile-inner
    const int xcd = lin & 7, jj = lin >> 3;      // jj in [0,168)
    const int nIdx  = jj / 56;                   // 0..2
    const int rem   = jj % 56;
    const int ntile = rem / 7;                   // 0..7 (32-col tiles)
    const int mtile = rem % 7;                   // 112-row tiles (exact)
    const int n     = nIdx * 8 + xcd;            // 0..23

    const int wave = tid >> 6, lane = tid & 63;
    const int rh = wave >> 1, cq = wave & 1;
    const int lrow = lane & 15, lci = lane >> 4;
    const int MC = (rh == 0) ? 4 : 3;

    // ---- A granules (pre-swizzled source, linear dest)
    const int nga = (wave < 3) ? 2 : 1;
    const u16* aSrc[2]; int aDst[2];
    #pragma unroll
    for (int i = 0; i < 2; ++i) {
        const int a = (i < nga) ? (wave + 4 * i) : 0;
        const int r = a * 16 + (lane >> 2);
        const int ach = (lane & 3) ^ ((r >> 1) & 3);
        aSrc[i] = Abf + ((size_t)(n * 56) * MR + mtile * 112 + r) * 32 + ach * 8;
        aDst[i] = a * 512 + lane * 8;
    }

    // ---- B granules: q = wave&1 fixed; gates g = (wave>>1) + 2i
    const int ngb = (wave < 2) ? 5 : 4;
    const int qb  = wave & 1;
    const int cb  = qb * 16 + (lane >> 2);           // local col 0..31
    const int chb = (lane & 3) ^ ((cb >> 1) & 3);
    const u16* bBase = WT0 + (size_t)n * 458752
                     + (size_t)(ntile * 32 + cb) * 32 + chb * 8;
    const int bDst0 = AB10 + qb * 512 + lane * 8;
    const int gb0 = wave >> 1;                        // first gate; step 2

    // ---- fragment read offsets
    int aro[4];
    #pragma unroll
    for (int m = 0; m < 4; ++m) {
        const int row = rh * 64 + m * 16 + lrow;
        aro[m] = row * 32 + ((lci ^ ((row >> 1) & 3)) << 3);
    }
    const int colr = cq * 16 + lrow;                  // local col 0..31
    const int bro  = AB10 + colr * 32 + ((lci ^ ((colr >> 1) & 3)) << 3);

    f32x4 acc[9][4];
    #pragma unroll
    for (int g = 0; g < 9; ++g)
        #pragma unroll
        for (int m = 0; m < 4; ++m) acc[g][m] = f32x4{0.f, 0.f, 0.f, 0.f};

    auto dma = [&](int kt, int buf) {
        u16* base = smem + buf * BUFE10;
        const size_t koA = (size_t)kt * (MR * 32);
        #pragma unroll
        for (int i = 0; i < 2; ++i)
            if (i < nga) gld16(aSrc[i] + koA, base + aDst[i]);
        const size_t koB = (size_t)kt * 8192;
        #pragma unroll
        for (int i = 0; i < 5; ++i)
            if (i < ngb) gld16(bBase + koB + (size_t)(gb0 + 2 * i) * 11010048,
                               base + bDst0 + (gb0 + 2 * i) * 1024);
    };
    auto waitw = [&]() {
        if (wave < 2)       { WAITVM(7); }
        else if (wave == 2) { WAITVM(6); }
        else                { WAITVM(5); }
    };
    auto domfma = [&](int buf) {
        const u16* base = smem + buf * BUFE10;
        s16x8 af[4];
        #pragma unroll
        for (int m = 0; m < 4; ++m)
            if (m < MC) af[m] = *(const s16x8*)(&base[aro[m]]);
        __builtin_amdgcn_s_setprio(1);
        #pragma unroll
        for (int g = 0; g < 9; ++g) {
            const s16x8 bf = *(const s16x8*)(&base[g * 1024 + bro]);
            #pragma unroll
            for (int m = 0; m < 4; ++m)
                if (m < MC)
                    acc[g][m] = __builtin_amdgcn_mfma_f32_16x16x32_bf16(af[m], bf, acc[g][m], 0, 0, 0);
        }
        __builtin_amdgcn_s_setprio(0);
    };

    // prologue: tiles 0,1 in flight; publish tile 0
    dma(0, 0); dma(1, 1);
    waitw(); BAR();
    for (int t3 = 0; t3 < 54; t3 += 3) {
        dma(t3 + 2, 2); domfma(0); waitw(); BAR();
        dma(t3 + 3, 0); domfma(1); waitw(); BAR();
        dma(t3 + 4, 1); domfma(2); waitw(); BAR();
    }
    domfma(0);                    // T = 54
    WAITVM(0); BAR();             // tile 55 fully landed
    domfma(1);                    // T = 55

    // ---- epilogue: bias + cell update, f32 stores (exact tiling, no guard)
    const int col = ntile * 32 + cq * 16 + lrow;
    float bv[9];
    #pragma unroll
    for (int g = 0; g < 9; ++g) bv[g] = Bias[(g * NN + n) * 256 + col];

    #pragma unroll
    for (int m = 0; m < 4; ++m) {
        if (m < MC) {
            #pragma unroll
            for (int i = 0; i < 4; ++i) {
                const int row = mtile * 112 + rh * 64 + m * 16 + (lane >> 4) * 4 + i;
                const size_t e = ((size_t)(row * NN + n)) * 256 + col;
                const float i_n  = sig_(acc[0][m][i] + bv[0]);
                const float f_lt = sig_(acc[1][m][i] + bv[1]);
                const float f_ft = sig_(acc[2][m][i] + bv[2]);
                const float f_rt = sig_(acc[3][m][i] + bv[3]);
                const float f_s  = sig_(acc[4][m][i] + bv[4]);
                const float f_gt = sig_(acc[5][m][i] + bv[5]);
                const float f_gs = sig_(acc[6][m][i] + bv[6]);
                const float o_n  = sig_(acc[7][m][i] + bv[7]);
                const float c_n  = tanh_(acc[8][m][i] + bv[8]);
                const float cb_ = (n > 0)      ? c_h[e - 256] : 0.f;
                const float ca_ = (n < NN - 1) ? c_h[e + 256] : 0.f;
                const float cs_ = (row % TT)   ? c_h[e - NN * 256] : 0.f;
                const float cn = f_lt * cb_ + f_ft * c_h[e] + f_rt * ca_
                               + f_s * cs_ + f_gt * c_g_t[e] + f_gs * c_g_s[e]
                               + i_n * c_n;
                c_h_new[e] = cn;
                h_new[e]   = o_n * tanh_(cn);
            }
        }
    }
}

// ===========================================================================
// Phase 1: counted-vmcnt pipeline + T14 split A-staging; n-major XCD decode.
// ===========================================================================
__global__ __launch_bounds__(256, 4) void fused_global5(
    const float* __restrict__ hn,   const float* __restrict__ g_t,
    const float* __restrict__ g_s,  const float* __restrict__ c_g_t,
    const float* __restrict__ c_g_s,
    const u16* __restrict__ WT1, const float* __restrict__ Bg,
    float* __restrict__ out2, float* __restrict__ out3,
    float* __restrict__ out4, float* __restrict__ out5)
{
    __shared__ u16 smem[2 * 2048 + 2 * 6144];

    const int tid = threadIdx.x;
    const int lin = blockIdx.x;
    // n-major XCD decode: xcd owns zz = zIdx*8+xcd (6 zz each)
    const int xcd = lin & 7, j = lin >> 3;   // j in [0,312)
    const int zIdx  = j / 52;                // 0..5
    const int rem   = j % 52;
    const int ntile = rem / 13;              // 0..3
    const int mtile = rem % 13;
    const int zz    = zIdx * 8 + xcd;        // 0..47
    const int n = zz % NN, grp = zz / NN;

    const float* xg = grp ? g_s : g_t;
    const float* cg = grp ? c_g_s : c_g_t;
    float* og  = grp ? out4 : out2;
    float* ocg = grp ? out5 : out3;

    const int s_r = tid >> 2, s_c = tid & 3;
    const int gr  = mtile * 64 + s_r;
    const bool mval = (gr < MR);
    const int ec = (gr * NN + n) * 256;

    const int wro = s_r * 32 + ((s_c ^ ((s_r >> 1) & 3)) << 3);

    const int wave = tid >> 6, lane = tid & 63;
    const int lrow = lane & 15, lci = lane >> 4;

    int aro[4];
    #pragma unroll
    for (int m = 0; m < 4; ++m) {
        const int row = m * 16 + lrow;
        aro[m] = row * 32 + ((lci ^ ((row >> 1) & 3)) << 3);
    }
    const int colr = wave * 16 + lrow;
    const int bro  = colr * 32 + ((lci ^ ((colr >> 1) & 3)) << 3);

    const u16* wbase = WT1 + (size_t)(grp * 3 * NN + n) * 131072
                           + (size_t)(ntile * 64) * 32 + wro;

    f32x4 acc[3][4];
    #pragma unroll
    for (int g = 0; g < 3; ++g)
        #pragma unroll
        for (int m = 0; m < 4; ++m) acc[g][m] = f32x4{0.f, 0.f, 0.f, 0.f};

    float4 aOlo, aOhi, aNlo, aNhi;

    auto loadA = [&](int kt, float4& lo, float4& hi) {
        const int K0 = kt * 32, koff = (K0 & 255) + s_c * 8;
        const float* src = ((K0 < 256) ? hn : xg) + ec + koff;
        lo = make_float4(0.f, 0.f, 0.f, 0.f); hi = lo;
        if (mval) { lo = *(const float4*)src; hi = *(const float4*)(src + 4); }
    };
    auto storeA = [&](int buf, const float4& lo, const float4& hi) {
        u16x8 aw;
        aw[0] = f2b(lo.x); aw[1] = f2b(lo.y); aw[2] = f2b(lo.z); aw[3] = f2b(lo.w);
        aw[4] = f2b(hi.x); aw[5] = f2b(hi.y); aw[6] = f2b(hi.z); aw[7] = f2b(hi.w);
        *(u16x8*)(&smem[buf * 2048 + wro]) = aw;
    };
    auto dmaB = [&](int kt, int buf) {
        const u16* wb = wbase + (size_t)kt * 8192;
        u16* dst = &smem[2 * 2048 + buf * 6144 + tid * 8];
        #pragma unroll
        for (int g = 0; g < 3; ++g)
            gld16(wb + (size_t)g * 3145728, dst + g * 2048);
    };
    auto domfma = [&](int buf) {
        const u16* Asb = smem + buf * 2048;
        const u16* Bsb = smem + 2 * 2048 + buf * 6144;
        s16x8 af[4];
        #pragma unroll
        for (int m = 0; m < 4; ++m) af[m] = *(const s16x8*)(&Asb[aro[m]]);
        __builtin_amdgcn_s_setprio(1);
        #pragma unroll
        for (int g = 0; g < 3; ++g) {
            const s16x8 bf = *(const s16x8*)(&Bsb[g * 2048 + bro]);
            #pragma unroll
            for (int m = 0; m < 4; ++m)
                acc[g][m] = __builtin_amdgcn_mfma_f32_16x16x32_bf16(af[m], bf, acc[g][m], 0, 0, 0);
        }
        __builtin_amdgcn_s_setprio(0);
    };

    loadA(0, aOlo, aOhi);
    dmaB(0, 0);
    storeA(0, aOlo, aOhi);
    loadA(1, aOlo, aOhi);
    dmaB(1, 1);
    WAITVL(5); BAR();
    for (int kt = 0; kt < 14; kt += 2) {
        domfma(0);
        BAR();
        loadA(kt + 2, aNlo, aNhi);
        dmaB(kt + 2, 0);
        storeA(1, aOlo, aOhi);
        WAITVL(5); BAR();
        domfma(1);
        BAR();
        loadA(kt + 3, aOlo, aOhi);
        dmaB(kt + 3, 1);
        storeA(0, aNlo, aNhi);
        WAITVL(5); BAR();
    }
    domfma(0);
    BAR();
    storeA(1, aOlo, aOhi);
    WAITVL(0); BAR();
    domfma(1);

    const int col = ntile * 64 + wave * 16 + lrow;
    float bv[3];
    #pragma unroll
    for (int g = 0; g < 3; ++g) bv[g] = Bg[((grp * 3 + g) * NN + n) * 256 + col];

    #pragma unroll
    for (int m = 0; m < 4; ++m) {
        #pragma unroll
        for (int i = 0; i < 4; ++i) {
            const int row = mtile * 64 + m * 16 + (lane >> 4) * 4 + i;
            if (row < MR) {
                const size_t e = ((size_t)(row * NN + n)) * 256 + col;
                const float f    = sig_(acc[0][m][i] + bv[0]);
                const float cand = tanh_(acc[1][m][i] + bv[1]);
                const float o    = sig_(acc[2][m][i] + bv[2]);
                const float cn = f * cg[e] + (1.f - f) * cand;
                ocg[e] = cn;
                og[e]  = o * tanh_(cn);
            }
        }
    }
}

extern "C" void kernel_launch(void* const* d_in, const int* in_sizes, int n_in,
                              void* d_out, int out_size, void* d_ws, size_t ws_size,
                              hipStream_t stream)
{
    const float* h     = (const float*)d_in[0];
    const float* c_h   = (const float*)d_in[1];
    const float* p     = (const float*)d_in[2];
    const float* g_t   = (const float*)d_in[3];
    const float* c_g_t = (const float*)d_in[4];
    const float* g_s   = (const float*)d_in[5];
    const float* c_g_s = (const float*)d_in[6];
    const float* U     = (const float*)d_in[7];
    const float* Wt    = (const float*)d_in[8];
    const float* Ws    = (const float*)d_in[9];
    const float* Zt    = (const float*)d_in[10];
    const float* Zs    = (const float*)d_in[11];
    const float* bb    = (const float*)d_in[12];
    const float* Wg    = (const float*)d_in[13];
    const float* Zg    = (const float*)d_in[14];
    const float* bg    = (const float*)d_in[15];

    float* out0 = (float*)d_out;        // h_new
    float* out1 = out0 + (size_t)SZT;   // c_h_new
    float* out2 = out1 + (size_t)SZT;   // g_t_new
    float* out3 = out2 + (size_t)SZT;   // c_g_t_new
    float* out4 = out3 + (size_t)SZT;   // g_s_new
    float* out5 = out4 + (size_t)SZT;   // c_g_s_new

    u16* wt0 = (u16*)d_ws;
    u16* wt1 = wt0 + WT0_ELEMS;
    u16* abf = wt1 + WT1_ELEMS;

    dim3 blk(256);
    prep_all<<<dim3(46272), blk, 0, stream>>>(U, Wt, Ws, Zt, Zs, Wg, Zg,
                                              p, h, g_t, g_s, wt0, wt1, abf);

    const int ldsBytes = 3 * BUFE10 * (int)sizeof(u16);   // 76800
    hipFuncSetAttribute((const void*)fused_cell10,
                        hipFuncAttributeMaxDynamicSharedMemorySize, ldsBytes);
    fused_cell10<<<dim3(1344), blk, ldsBytes, stream>>>(
        c_h, c_g_t, c_g_s, abf, wt0, bb, out0, out1);
    fused_global5<<<dim3(2496), blk, 0, stream>>>(
        out0, g_t, g_s, c_g_t, c_g_s, wt1, bg, out2, out3, out4, out5);
}